// Round 9
// baseline (322.836 us; speedup 1.0000x reference)
//
#include <hip/hip_runtime.h>
#include <hip/hip_fp16.h>
#include <math.h>

#define N_NODES 100000
#define N_EDGES 3200000
#define GRID_G 6250       // ceil(100000/16); 6250*16 == N_NODES exactly
#define NSB 782           // ceil(100000/128) super-buckets
#define SB_NODES 128
#define SBCAP 5120        // mean 4096, std 64 -> +16 sigma
#define E_BLK 12800       // edges per k_part block
#define PART_BLOCKS 250   // 500-block variant regressed (scatter-write contention)
#define PART_THREADS 1024
#define GRID_DEC 12500    // 3.2M / 256, 1 edge per thread

// ---------------- ws float layout (element offsets) ----------------
#define OFF_DINV 0
#define OFF_C    100016
#define OFF_ZS16 200032      // 100000 x 16 halfs (dinv-scaled z), 32B rows
#define OFF_T16  1000048     // 100000 x 16 halfs, 32B rows
#define OFF_U    1800064     // (unused; layout kept)
#define OFF_YT   3400080     // 100000 x 32B (16 fp16), 64B-aligned pairs
#define OFF_ST   4200080     // 100000 x 8B (4 fp16: r1,r2,r3,r4)
#define OFF_PR   6604720
#define OFF_PB   6604736
#define OFF_ABG  6604752     // beta, gamma/2, lam+, lam-, k1, k2
#define OFF_L    6604768     // 16x16 Cholesky factor of G
#define FLOAT_TOTAL 6605024
// int region (elements into (int*)(ws + FLOAT_TOTAL))
#define IOFF_GCUR 0
#define IOFF_BEG  1024
#define IOFF_CNT  101024
#define IOFF_BUF  201024     // 782*5120
#define IOFF_CSR  4204864    // 782*5120
// ws total ~59 MB

// ---- half helpers ----
__device__ inline float4 h4_to_f4(uint2 v) {
    __half2 a = *reinterpret_cast<__half2*>(&v.x);
    __half2 b = *reinterpret_cast<__half2*>(&v.y);
    float2 fa = __half22float2(a), fb = __half22float2(b);
    return make_float4(fa.x, fa.y, fb.x, fb.y);
}
__device__ inline uint2 f4_to_h4(float4 f) {
    uint2 r;
    __half2 a = __floats2half2_rn(f.x, f.y);
    __half2 b = __floats2half2_rn(f.z, f.w);
    r.x = *reinterpret_cast<unsigned*>(&a);
    r.y = *reinterpret_cast<unsigned*>(&b);
    return r;
}
__device__ inline float4 pack_h8(float4 a, float4 b) {
    float4 r;
    __half2* p = reinterpret_cast<__half2*>(&r);
    p[0] = __floats2half2_rn(a.x, a.y);
    p[1] = __floats2half2_rn(a.z, a.w);
    p[2] = __floats2half2_rn(b.x, b.y);
    p[3] = __floats2half2_rn(b.z, b.w);
    return r;
}
__device__ inline unsigned h2bits(float a, float b) {
    __half2 h = __floats2half2_rn(a, b);
    return *reinterpret_cast<unsigned*>(&h);
}
__device__ inline float2 bits2f2(unsigned v) {
    __half2 h = *reinterpret_cast<__half2*>(&v);
    return __half22float2(h);
}
__device__ inline float hdot8f(float4 a, float4 b) {
    const __half2* pa = reinterpret_cast<const __half2*>(&a);
    const __half2* pb = reinterpret_cast<const __half2*>(&b);
    float s = 0.0f;
    #pragma unroll
    for (int i = 0; i < 4; i++) {
        float2 fa = __half22float2(pa[i]);
        float2 fb = __half22float2(pb[i]);
        s += fa.x * fb.x + fa.y * fb.y;
    }
    return s;
}
// accumulate 8 halfs (uint4) into two float4 accumulators
__device__ inline void acc8(float4& lo, float4& hi, uint4 v) {
    float2 p0 = __half22float2(*reinterpret_cast<__half2*>(&v.x));
    float2 p1 = __half22float2(*reinterpret_cast<__half2*>(&v.y));
    float2 p2 = __half22float2(*reinterpret_cast<__half2*>(&v.z));
    float2 p3 = __half22float2(*reinterpret_cast<__half2*>(&v.w));
    lo.x += p0.x; lo.y += p0.y; lo.z += p1.x; lo.w += p1.y;
    hi.x += p2.x; hi.y += p2.y; hi.z += p3.x; hi.w += p3.y;
}
__device__ inline void bfly4(float4& v, int m) {
    v.x += __shfl_xor(v.x, m, 64);
    v.y += __shfl_xor(v.y, m, 64);
    v.z += __shfl_xor(v.z, m, 64);
    v.w += __shfl_xor(v.w, m, 64);
}

// ---- shared-memory unions for the merged part+consts kernel ----
struct ConstsSh {
    float sW1t[16 * 256];
    float sM[16 * 257];
    float sb1[256];
    float sb2[256];
    float sR[256];
    float sG[256];
    float sLf[256];
};
struct PartSh {
    int hist[4][NSB];
    int cur[NSB];
};

// ---- phase A: LDS-staged binning + concurrent consts block ----
__global__ void __launch_bounds__(PART_THREADS)
k_part(const int* __restrict__ src, const int* __restrict__ dst,
       int* __restrict__ gcur, int* __restrict__ buf,
       const float* __restrict__ W1, const float* __restrict__ b1,
       const float* __restrict__ W2, const float* __restrict__ b2,
       float* __restrict__ ws) {
    __shared__ union { ConstsSh c; PartSh p; } sh;
    int t = threadIdx.x;

    if (blockIdx.x == PART_BLOCKS) {
        bool act = t < 256;
        if (act) {
            #pragma unroll
            for (int r = 0; r < 16; r++)
                sh.c.sW1t[t * 16 + r] = W1[r * 256 + t];
            sh.c.sb1[t] = b1[t];
            sh.c.sb2[t] = b2[t];
        }
        __syncthreads();
        if (act) {
            float acc[16];
            #pragma unroll
            for (int i = 0; i < 16; i++) acc[i] = 0.0f;
            float raccv = 0.0f;
            for (int kk = 0; kk < 256; kk += 8) {
                float w2v[8];
                #pragma unroll
                for (int u = 0; u < 8; u++)
                    w2v[u] = W2[(kk + u) * 256 + t];
                #pragma unroll
                for (int u = 0; u < 8; u++) {
                    #pragma unroll
                    for (int i = 0; i < 16; i++)
                        acc[i] += sh.c.sW1t[(kk + u) * 16 + i] * w2v[u];
                    raccv += sh.c.sb1[kk + u] * w2v[u];
                }
            }
            #pragma unroll
            for (int i = 0; i < 16; i++) sh.c.sM[i * 257 + t] = acc[i];
            sh.c.sR[t] = raccv;
        }
        __syncthreads();
        if (act) {
            int i = t >> 4, j = t & 15;
            float gg = 0.0f;
            for (int tt = 0; tt < 256; tt++)
                gg += sh.c.sM[i * 257 + tt] * sh.c.sM[j * 257 + tt];
            sh.c.sG[t] = gg;
        }
        if (t < 16) {
            float a = 0.0f, b = 0.0f;
            for (int tt = 0; tt < 256; tt++) {
                a += sh.c.sM[t * 257 + tt] * sh.c.sR[tt];
                b += sh.c.sM[t * 257 + tt] * sh.c.sb2[tt];
            }
            ws[OFF_PR + t] = a;
            ws[OFF_PB + t] = b;
        }
        if (t == 0) {
            float al = 0.0f, be = 0.0f, ga = 0.0f;
            for (int tt = 0; tt < 256; tt++) {
                al += sh.c.sR[tt] * sh.c.sR[tt];
                be += sh.c.sR[tt] * sh.c.sb2[tt];
                ga += sh.c.sb2[tt] * sh.c.sb2[tt];
            }
            float disc = sqrtf(al * al + 4.0f);
            float lp = 0.5f * (al + disc);
            float lm = 0.5f * (al - disc);
            float k1 = sqrtf(lp / (lp * lp + 1.0f));
            float k2 = sqrtf(-lm / (lm * lm + 1.0f));
            ws[OFF_ABG + 0] = be;
            ws[OFF_ABG + 1] = 0.5f * ga;
            ws[OFF_ABG + 2] = lp;
            ws[OFF_ABG + 3] = lm;
            ws[OFF_ABG + 4] = k1;
            ws[OFF_ABG + 5] = k2;
        }
        __syncthreads();
        if (act) sh.c.sLf[t] = 0.0f;
        __syncthreads();
        for (int j = 0; j < 16; j++) {
            if (t == j) {
                float s = sh.c.sG[j * 16 + j];
                for (int k = 0; k < j; k++)
                    s -= sh.c.sLf[j * 16 + k] * sh.c.sLf[j * 16 + k];
                sh.c.sLf[j * 16 + j] = sqrtf(fmaxf(s, 1e-20f));
            }
            __syncthreads();
            if (t > j && t < 16) {
                float s = sh.c.sG[t * 16 + j];
                for (int k = 0; k < j; k++)
                    s -= sh.c.sLf[t * 16 + k] * sh.c.sLf[j * 16 + k];
                sh.c.sLf[t * 16 + j] = s / sh.c.sLf[j * 16 + j];
            }
            __syncthreads();
        }
        if (act) ws[OFF_L + t] = sh.c.sLf[t];
        return;
    }

    // ================= binning path =================
    int cp = t >> 8;
    int base = blockIdx.x * E_BLK;
    for (int i = t; i < 4 * NSB; i += PART_THREADS) ((int*)sh.p.hist)[i] = 0;
    __syncthreads();
    for (int i = t; i < E_BLK; i += PART_THREADS) {
        int e = base + i;
        if (e < N_EDGES)
            atomicAdd(&sh.p.hist[cp][__builtin_nontemporal_load(dst + e) >> 7], 1);
    }
    __syncthreads();
    for (int i = t; i < NSB; i += PART_THREADS) {
        int h = sh.p.hist[0][i] + sh.p.hist[1][i] + sh.p.hist[2][i] + sh.p.hist[3][i];
        sh.p.cur[i] = (h > 0) ? atomicAdd(&gcur[i], h) : 0;
    }
    __syncthreads();
    for (int i = t; i < E_BLK; i += PART_THREADS) {
        int e = base + i;
        if (e >= N_EDGES) continue;
        int d = __builtin_nontemporal_load(dst + e);
        int s = __builtin_nontemporal_load(src + e);
        int sb = d >> 7;
        int pos = atomicAdd(&sh.p.cur[sb], 1);
        if (pos < SBCAP) buf[sb * SBCAP + pos] = s | ((d & 127) << 17);
    }
}

// ---- phase B: per-SB counting sort -> exact CSR, fused dinv + zs16 ----
__global__ void k_sort(const float* __restrict__ z, const int* __restrict__ gcur,
                       const int* __restrict__ buf, int* __restrict__ csr,
                       int* __restrict__ begA, int* __restrict__ cntA,
                       float* __restrict__ ws) {
    __shared__ int pay[SBCAP];
    __shared__ int h[SB_NODES + 1];
    __shared__ int lcur[SB_NODES];
    __shared__ float sdv[SB_NODES];
    int sb = blockIdx.x, t = threadIdx.x;
    int n = gcur[sb];
    if (n > SBCAP) n = SBCAP;
    for (int i = t; i < n; i += 256) pay[i] = buf[sb * SBCAP + i];
    if (t <= SB_NODES) h[t] = 0;
    __syncthreads();
    for (int i = t; i < n; i += 256) atomicAdd(&h[(pay[i] >> 17) + 1], 1);
    __syncthreads();
    int mydeg = 0;
    if (t < SB_NODES) { mydeg = h[t + 1]; h[t + 1] = (mydeg + 3) & ~3; }
    __syncthreads();
    for (int off = 1; off <= SB_NODES; off <<= 1) {
        int v = 0;
        if (t <= SB_NODES && t >= off) v = h[t - off];
        __syncthreads();
        if (t <= SB_NODES) h[t] += v;
        __syncthreads();
    }
    int n0 = sb * SB_NODES;
    if (t < SB_NODES) {
        lcur[t] = h[t];
        float dv = rsqrtf((float)(mydeg + 1));
        sdv[t] = dv;
        if (n0 + t < N_NODES) {
            cntA[n0 + t] = mydeg;
            begA[n0 + t] = sb * SBCAP + h[t];
            ws[OFF_DINV + n0 + t] = dv;
        }
    }
    __syncthreads();
    {
        int nl = t >> 1, half = t & 1;
        int node = n0 + nl;
        if (node < N_NODES) {
            const float4* zr = (const float4*)(z + (size_t)node * 16) + 2 * half;
            float dv = sdv[nl];
            float4 a = zr[0], b = zr[1];
            a = make_float4(a.x * dv, a.y * dv, a.z * dv, a.w * dv);
            b = make_float4(b.x * dv, b.y * dv, b.z * dv, b.w * dv);
            ((float4*)((__half*)(ws + OFF_ZS16) + (size_t)node * 16))[half] = pack_h8(a, b);
        }
    }
    for (int i = t; i < n; i += 256) {
        int p = pay[i];
        int dl = p >> 17;
        int pos = atomicAdd(&lcur[dl], 1);
        if (pos < SBCAP) csr[sb * SBCAP + pos] = p & 0x1FFFF;
    }
}

// ---- pass 1 (transposed gather): each lane owns whole edges, loads full
//      32B rows as 2x16B (64 distinct lines per VMEM instr vs 16 before),
//      accumulates 16 dims in registers, 4-step butterfly over the
//      16-lane group leaves the full sum in every lane. ----
__global__ void k_gather1(const int* __restrict__ cntA, const int* __restrict__ begA,
                          const int* __restrict__ csr, float* __restrict__ ws) {
    int tid = threadIdx.x;
    int lane = tid & 15;
    int g = tid >> 4;
    int d = blockIdx.x * 16 + g;   // GRID_G*16 == N_NODES exactly
    const float* dinv = ws + OFF_DINV;
    const __half* zs = (const __half*)(ws + OFF_ZS16);
    float dd = dinv[d];
    float dv2 = dd * dd;
    int deg = cntA[d];
    int beg = begA[d];
    float4 f0 = make_float4(0.f,0.f,0.f,0.f), f1 = f0, f2 = f0, f3 = f0;
    float csum = 0.0f;
    int j = lane;
    for (; j + 16 < deg; j += 32) {
        int s0 = csr[beg + j];
        int s1 = csr[beg + j + 16];
        uint4 a0 = *(const uint4*)(zs + (size_t)s0 * 16);
        uint4 a1 = *(const uint4*)(zs + (size_t)s0 * 16 + 8);
        uint4 b0 = *(const uint4*)(zs + (size_t)s1 * 16);
        uint4 b1 = *(const uint4*)(zs + (size_t)s1 * 16 + 8);
        float dv = dinv[s0] + dinv[s1];
        __builtin_amdgcn_sched_barrier(0);   // all loads issued before use
        acc8(f0, f1, a0); acc8(f2, f3, a1);
        acc8(f0, f1, b0); acc8(f2, f3, b1);
        csum += dv;
    }
    if (j < deg) {
        int s0 = csr[beg + j];
        uint4 a0 = *(const uint4*)(zs + (size_t)s0 * 16);
        uint4 a1 = *(const uint4*)(zs + (size_t)s0 * 16 + 8);
        float dv = dinv[s0];
        __builtin_amdgcn_sched_barrier(0);
        acc8(f0, f1, a0); acc8(f2, f3, a1);
        csum += dv;
    }
    #pragma unroll
    for (int m = 1; m <= 8; m <<= 1) {
        bfly4(f0, m); bfly4(f1, m); bfly4(f2, m); bfly4(f3, m);
        csum += __shfl_xor(csum, m, 64);
    }
    // every lane now holds the full neighbor-sum; lanes 0-3 write chunks
    if (lane < 4) {
        float4 zq = h4_to_f4(((const uint2*)(zs + (size_t)d * 16))[lane]);
        float4 fq = f0;
        if (lane == 1) fq = f1;
        if (lane == 2) fq = f2;
        if (lane == 3) fq = f3;
        float4 o = make_float4(dv2 * (fq.x + zq.x), dv2 * (fq.y + zq.y),
                               dv2 * (fq.z + zq.z), dv2 * (fq.w + zq.w));
        ((uint2*)((__half*)(ws + OFF_T16) + (size_t)d * 16))[lane] = f4_to_h4(o);
    }
    if (lane == 0) (ws + OFF_C)[d] = dd * csum + dv2;
}

// ---- pass 2 + pack fused (transposed gather): butterfly gives every lane
//      the full u vector, so each lane computes one y column locally;
//      pack via 2 shuffles; A/B/st on lane 0. ----
__global__ void k_gather2(const int* __restrict__ cntA, const int* __restrict__ begA,
                          const int* __restrict__ csr, float* __restrict__ ws) {
    __shared__ float sL[256];
    __shared__ float spr[16];
    __shared__ float spb[16];
    __shared__ float sprm[8];
    int tid = threadIdx.x;
    sL[tid] = ws[OFF_L + tid];
    if (tid < 16) { spr[tid] = ws[OFF_PR + tid]; spb[tid] = ws[OFF_PB + tid]; }
    if (tid < 8) sprm[tid] = ws[OFF_ABG + tid];
    __syncthreads();

    int lane = tid & 15;
    int g = tid >> 4;
    int d = blockIdx.x * 16 + g;   // exact grid, no guard
    const float* dinv = ws + OFF_DINV;
    const __half* t16 = (const __half*)(ws + OFF_T16);
    float dd = dinv[d];
    int deg = cntA[d];
    int beg = begA[d];
    float4 f0 = make_float4(0.f,0.f,0.f,0.f), f1 = f0, f2 = f0, f3 = f0;
    int j = lane;
    for (; j + 16 < deg; j += 32) {
        int s0 = csr[beg + j];
        int s1 = csr[beg + j + 16];
        uint4 a0 = *(const uint4*)(t16 + (size_t)s0 * 16);
        uint4 a1 = *(const uint4*)(t16 + (size_t)s0 * 16 + 8);
        uint4 b0 = *(const uint4*)(t16 + (size_t)s1 * 16);
        uint4 b1 = *(const uint4*)(t16 + (size_t)s1 * 16 + 8);
        __builtin_amdgcn_sched_barrier(0);
        acc8(f0, f1, a0); acc8(f2, f3, a1);
        acc8(f0, f1, b0); acc8(f2, f3, b1);
    }
    if (j < deg) {
        int s0 = csr[beg + j];
        uint4 a0 = *(const uint4*)(t16 + (size_t)s0 * 16);
        uint4 a1 = *(const uint4*)(t16 + (size_t)s0 * 16 + 8);
        __builtin_amdgcn_sched_barrier(0);
        acc8(f0, f1, a0); acc8(f2, f3, a1);
    }
    #pragma unroll
    for (int m = 1; m <= 8; m <<= 1) {
        bfly4(f0, m); bfly4(f1, m); bfly4(f2, m); bfly4(f3, m);
    }
    // u = dd * (sum + own t16 row); every lane computes the full u
    uint4 t0 = *(const uint4*)(t16 + (size_t)d * 16);
    uint4 t1 = *(const uint4*)(t16 + (size_t)d * 16 + 8);
    float4 z0 = make_float4(0.f,0.f,0.f,0.f), z1 = z0, z2 = z0, z3 = z0;
    acc8(z0, z1, t0); acc8(z2, z3, t1);
    float4 u0 = make_float4(dd*(f0.x+z0.x), dd*(f0.y+z0.y), dd*(f0.z+z0.z), dd*(f0.w+z0.w));
    float4 u1 = make_float4(dd*(f1.x+z1.x), dd*(f1.y+z1.y), dd*(f1.z+z1.z), dd*(f1.w+z1.w));
    float4 u2 = make_float4(dd*(f2.x+z2.x), dd*(f2.y+z2.y), dd*(f2.z+z2.z), dd*(f2.w+z2.w));
    float4 u3 = make_float4(dd*(f3.x+z3.x), dd*(f3.y+z3.y), dd*(f3.z+z3.z), dd*(f3.w+z3.w));
    // lane computes y[lane] = u . L[:,lane]
    float yl = u0.x * sL[0*16+lane]  + u0.y * sL[1*16+lane]
             + u0.z * sL[2*16+lane]  + u0.w * sL[3*16+lane]
             + u1.x * sL[4*16+lane]  + u1.y * sL[5*16+lane]
             + u1.z * sL[6*16+lane]  + u1.w * sL[7*16+lane]
             + u2.x * sL[8*16+lane]  + u2.y * sL[9*16+lane]
             + u2.z * sL[10*16+lane] + u2.w * sL[11*16+lane]
             + u3.x * sL[12*16+lane] + u3.y * sL[13*16+lane]
             + u3.z * sL[14*16+lane] + u3.w * sL[15*16+lane];
    // pack: even lane -> h2(y_l, y_{l+1}); lane 4q writes uint2 {w, w from l^2}
    float yn = __shfl_xor(yl, 1, 64);
    unsigned w = h2bits(yl, yn);
    unsigned w2 = __shfl_xor(w, 2, 64);
    if ((lane & 3) == 0)
        ((uint2*)(ws + OFF_YT))[(size_t)d * 4 + (lane >> 2)] = make_uint2(w, w2);
    if (lane == 0) {
        float pA = u0.x*spr[0]  + u0.y*spr[1]  + u0.z*spr[2]  + u0.w*spr[3]
                 + u1.x*spr[4]  + u1.y*spr[5]  + u1.z*spr[6]  + u1.w*spr[7]
                 + u2.x*spr[8]  + u2.y*spr[9]  + u2.z*spr[10] + u2.w*spr[11]
                 + u3.x*spr[12] + u3.y*spr[13] + u3.z*spr[14] + u3.w*spr[15];
        float pB = u0.x*spb[0]  + u0.y*spb[1]  + u0.z*spb[2]  + u0.w*spb[3]
                 + u1.x*spb[4]  + u1.y*spb[5]  + u1.z*spb[6]  + u1.w*spb[7]
                 + u2.x*spb[8]  + u2.y*spb[9]  + u2.z*spb[10] + u2.w*spb[11]
                 + u3.x*spb[12] + u3.y*spb[13] + u3.z*spb[14] + u3.w*spb[15];
        float beta = sprm[0], gh = sprm[1], lp = sprm[2], lm = sprm[3];
        float k1 = sprm[4], k2 = sprm[5];
        float ci = (ws + OFF_C)[d];
        float Ap = pA + beta;
        float Bp = pB + gh;
        float r1 = k1 * (lp * ci + Ap);
        float r2 = k2 * (lm * ci + Ap);
        const float inv_s2 = 0.70710678118654752f;
        float r3 = (Bp + 1.0f) * inv_s2;
        float r4 = (Bp - 1.0f) * inv_s2;
        ((uint2*)(ws + OFF_ST))[d] = make_uint2(h2bits(r1, r2), h2bits(r3, r4));
    }
}

// ---- decoder, 1 edge per thread ----
__global__ void k_decode(const int* __restrict__ src, const int* __restrict__ dst,
                         const float* __restrict__ ws, float* __restrict__ out) {
    int e = blockIdx.x * 256 + threadIdx.x;   // GRID_DEC*256 == N_EDGES exactly
    const float4* yt = (const float4*)(ws + OFF_YT);
    const uint2*  st = (const uint2*)(ws + OFF_ST);
    int s = __builtin_nontemporal_load(src + e);
    int d = __builtin_nontemporal_load(dst + e);
    float4 sy0 = yt[2 * (size_t)s];
    float4 sy1 = yt[2 * (size_t)s + 1];
    float4 dy0 = yt[2 * (size_t)d];
    float4 dy1 = yt[2 * (size_t)d + 1];
    uint2  ssc = st[s];
    uint2  dsc = st[d];
    __builtin_amdgcn_sched_barrier(0);   // all 6 gathers stay in flight
    float v = hdot8f(sy0, dy0) + hdot8f(sy1, dy1);
    float2 ra = bits2f2(ssc.x), rb = bits2f2(dsc.x);
    float2 rc = bits2f2(ssc.y), rd = bits2f2(dsc.y);
    v += ra.x * rb.x - ra.y * rb.y + rc.x * rd.x - rc.y * rd.y;
    __builtin_nontemporal_store(1.0f / (1.0f + expf(-v)), out + e);
}

extern "C" void kernel_launch(void* const* d_in, const int* in_sizes, int n_in,
                              void* d_out, int out_size, void* d_ws, size_t ws_size,
                              hipStream_t stream) {
    const float* z  = (const float*)d_in[0];
    const int*   ei = (const int*)d_in[1];
    const float* W1 = (const float*)d_in[2];
    const float* b1 = (const float*)d_in[3];
    const float* W2 = (const float*)d_in[4];
    const float* b2 = (const float*)d_in[5];
    float* out = (float*)d_out;
    float* ws  = (float*)d_ws;
    int*   wi  = (int*)(ws + FLOAT_TOTAL);

    const int* src = ei;
    const int* dst = ei + N_EDGES;

    int* gcur = wi + IOFF_GCUR;
    int* begA = wi + IOFF_BEG;
    int* cntA = wi + IOFF_CNT;
    int* buf  = wi + IOFF_BUF;
    int* csr  = wi + IOFF_CSR;

    hipMemsetAsync(gcur, 0, 1024 * sizeof(int), stream);
    k_part    <<<PART_BLOCKS + 1, PART_THREADS, 0, stream>>>(src, dst, gcur, buf,
                                                             W1, b1, W2, b2, ws);
    k_sort    <<<NSB, 256, 0, stream>>>(z, gcur, buf, csr, begA, cntA, ws);
    k_gather1 <<<GRID_G, 256, 0, stream>>>(cntA, begA, csr, ws);
    k_gather2 <<<GRID_G, 256, 0, stream>>>(cntA, begA, csr, ws);
    k_decode  <<<GRID_DEC, 256, 0, stream>>>(src, dst, ws, out);
}

// Round 10
// 283.990 us; speedup vs baseline: 1.1368x; 1.1368x over previous
//
#include <hip/hip_runtime.h>
#include <hip/hip_fp16.h>
#include <math.h>

#define N_NODES 100000
#define N_EDGES 3200000
#define GRID_N 391        // ceil(100000/256)
#define GRID_G 6250       // ceil(100000/16)
#define NSB 782           // ceil(100000/128) super-buckets
#define SB_NODES 128
#define SBCAP 5120        // mean 4096, std 64 -> +16 sigma
#define E_BLK 12800       // edges per k_part block
#define PART_BLOCKS 250   // 500-block variant regressed (scatter-write contention)
#define PART_THREADS 1024
#define GRID_DEC 12500    // 3.2M / 256, 1 edge per thread

// ---------------- ws float layout (element offsets) ----------------
#define OFF_DINV 0
#define OFF_C    100016
#define OFF_ZS16 200032      // 100000 x 16 halfs (dinv-scaled z)
#define OFF_T16  1000048     // 100000 x 16 halfs
#define OFF_U    1800064     // 100000 x 16 fp32
#define OFF_YT   3400080     // 100000 x 32B (16 fp16), 16B-aligned
#define OFF_ST   4200080     // 100000 x 8B (4 fp16: r1,r2,r3,r4)
#define OFF_PR   6604720
#define OFF_PB   6604736
#define OFF_ABG  6604752     // beta, gamma/2, lam+, lam-, k1, k2
#define OFF_L    6604768     // 16x16 Cholesky factor of G
#define FLOAT_TOTAL 6605024
// int region (elements into (int*)(ws + FLOAT_TOTAL))
#define IOFF_GCUR 0
#define IOFF_BEG  1024
#define IOFF_CNT  101024
#define IOFF_BUF  201024     // 782*5120
#define IOFF_CSR  4204864    // 782*5120
// ws total ~59 MB

// ---- half helpers ----
__device__ inline float4 h4_to_f4(uint2 v) {
    __half2 a = *reinterpret_cast<__half2*>(&v.x);
    __half2 b = *reinterpret_cast<__half2*>(&v.y);
    float2 fa = __half22float2(a), fb = __half22float2(b);
    return make_float4(fa.x, fa.y, fb.x, fb.y);
}
__device__ inline uint2 f4_to_h4(float4 f) {
    uint2 r;
    __half2 a = __floats2half2_rn(f.x, f.y);
    __half2 b = __floats2half2_rn(f.z, f.w);
    r.x = *reinterpret_cast<unsigned*>(&a);
    r.y = *reinterpret_cast<unsigned*>(&b);
    return r;
}
__device__ inline float4 pack_h8(float4 a, float4 b) {
    float4 r;
    __half2* p = reinterpret_cast<__half2*>(&r);
    p[0] = __floats2half2_rn(a.x, a.y);
    p[1] = __floats2half2_rn(a.z, a.w);
    p[2] = __floats2half2_rn(b.x, b.y);
    p[3] = __floats2half2_rn(b.z, b.w);
    return r;
}
__device__ inline unsigned h2bits(float a, float b) {
    __half2 h = __floats2half2_rn(a, b);
    return *reinterpret_cast<unsigned*>(&h);
}
__device__ inline float2 bits2f2(unsigned v) {
    __half2 h = *reinterpret_cast<__half2*>(&v);
    return __half22float2(h);
}
__device__ inline float hdot8f(float4 a, float4 b) {
    const __half2* pa = reinterpret_cast<const __half2*>(&a);
    const __half2* pb = reinterpret_cast<const __half2*>(&b);
    float s = 0.0f;
    #pragma unroll
    for (int i = 0; i < 4; i++) {
        float2 fa = __half22float2(pa[i]);
        float2 fb = __half22float2(pb[i]);
        s += fa.x * fb.x + fa.y * fb.y;
    }
    return s;
}
__device__ inline void acc4(float4& acc, uint2 g) {
    float4 f = h4_to_f4(g);
    acc.x += f.x; acc.y += f.y; acc.z += f.z; acc.w += f.w;
}

// ---- shared-memory unions for the merged part+consts kernel ----
struct ConstsSh {
    float sW1t[16 * 256];
    float sM[16 * 257];
    float sb1[256];
    float sb2[256];
    float sR[256];
    float sG[256];
    float sLf[256];
};
struct PartSh {
    int hist[4][NSB];
    int cur[NSB];
};

// ---- phase A: LDS-staged binning + concurrent consts block ----
__global__ void __launch_bounds__(PART_THREADS)
k_part(const int* __restrict__ src, const int* __restrict__ dst,
       int* __restrict__ gcur, int* __restrict__ buf,
       const float* __restrict__ W1, const float* __restrict__ b1,
       const float* __restrict__ W2, const float* __restrict__ b2,
       float* __restrict__ ws) {
    __shared__ union { ConstsSh c; PartSh p; } sh;
    int t = threadIdx.x;

    if (blockIdx.x == PART_BLOCKS) {
        bool act = t < 256;
        if (act) {
            #pragma unroll
            for (int r = 0; r < 16; r++)
                sh.c.sW1t[t * 16 + r] = W1[r * 256 + t];
            sh.c.sb1[t] = b1[t];
            sh.c.sb2[t] = b2[t];
        }
        __syncthreads();
        if (act) {
            float acc[16];
            #pragma unroll
            for (int i = 0; i < 16; i++) acc[i] = 0.0f;
            float raccv = 0.0f;
            for (int kk = 0; kk < 256; kk += 8) {
                float w2v[8];
                #pragma unroll
                for (int u = 0; u < 8; u++)
                    w2v[u] = W2[(kk + u) * 256 + t];
                #pragma unroll
                for (int u = 0; u < 8; u++) {
                    #pragma unroll
                    for (int i = 0; i < 16; i++)
                        acc[i] += sh.c.sW1t[(kk + u) * 16 + i] * w2v[u];
                    raccv += sh.c.sb1[kk + u] * w2v[u];
                }
            }
            #pragma unroll
            for (int i = 0; i < 16; i++) sh.c.sM[i * 257 + t] = acc[i];
            sh.c.sR[t] = raccv;
        }
        __syncthreads();
        if (act) {
            int i = t >> 4, j = t & 15;
            float gg = 0.0f;
            for (int tt = 0; tt < 256; tt++)
                gg += sh.c.sM[i * 257 + tt] * sh.c.sM[j * 257 + tt];
            sh.c.sG[t] = gg;
        }
        if (t < 16) {
            float a = 0.0f, b = 0.0f;
            for (int tt = 0; tt < 256; tt++) {
                a += sh.c.sM[t * 257 + tt] * sh.c.sR[tt];
                b += sh.c.sM[t * 257 + tt] * sh.c.sb2[tt];
            }
            ws[OFF_PR + t] = a;
            ws[OFF_PB + t] = b;
        }
        if (t == 0) {
            float al = 0.0f, be = 0.0f, ga = 0.0f;
            for (int tt = 0; tt < 256; tt++) {
                al += sh.c.sR[tt] * sh.c.sR[tt];
                be += sh.c.sR[tt] * sh.c.sb2[tt];
                ga += sh.c.sb2[tt] * sh.c.sb2[tt];
            }
            float disc = sqrtf(al * al + 4.0f);
            float lp = 0.5f * (al + disc);
            float lm = 0.5f * (al - disc);
            float k1 = sqrtf(lp / (lp * lp + 1.0f));
            float k2 = sqrtf(-lm / (lm * lm + 1.0f));
            ws[OFF_ABG + 0] = be;
            ws[OFF_ABG + 1] = 0.5f * ga;
            ws[OFF_ABG + 2] = lp;
            ws[OFF_ABG + 3] = lm;
            ws[OFF_ABG + 4] = k1;
            ws[OFF_ABG + 5] = k2;
        }
        __syncthreads();
        if (act) sh.c.sLf[t] = 0.0f;
        __syncthreads();
        // parallel Cholesky: 16 steps, column-parallel
        for (int j = 0; j < 16; j++) {
            if (t == j) {
                float s = sh.c.sG[j * 16 + j];
                for (int k = 0; k < j; k++)
                    s -= sh.c.sLf[j * 16 + k] * sh.c.sLf[j * 16 + k];
                sh.c.sLf[j * 16 + j] = sqrtf(fmaxf(s, 1e-20f));
            }
            __syncthreads();
            if (t > j && t < 16) {
                float s = sh.c.sG[t * 16 + j];
                for (int k = 0; k < j; k++)
                    s -= sh.c.sLf[t * 16 + k] * sh.c.sLf[j * 16 + k];
                sh.c.sLf[t * 16 + j] = s / sh.c.sLf[j * 16 + j];
            }
            __syncthreads();
        }
        if (act) ws[OFF_L + t] = sh.c.sLf[t];
        return;
    }

    // ================= binning path =================
    int cp = t >> 8;
    int base = blockIdx.x * E_BLK;
    for (int i = t; i < 4 * NSB; i += PART_THREADS) ((int*)sh.p.hist)[i] = 0;
    __syncthreads();
    for (int i = t; i < E_BLK; i += PART_THREADS) {
        int e = base + i;
        if (e < N_EDGES)
            atomicAdd(&sh.p.hist[cp][__builtin_nontemporal_load(dst + e) >> 7], 1);
    }
    __syncthreads();
    for (int i = t; i < NSB; i += PART_THREADS) {
        int h = sh.p.hist[0][i] + sh.p.hist[1][i] + sh.p.hist[2][i] + sh.p.hist[3][i];
        sh.p.cur[i] = (h > 0) ? atomicAdd(&gcur[i], h) : 0;
    }
    __syncthreads();
    for (int i = t; i < E_BLK; i += PART_THREADS) {
        int e = base + i;
        if (e >= N_EDGES) continue;
        int d = __builtin_nontemporal_load(dst + e);
        int s = __builtin_nontemporal_load(src + e);
        int sb = d >> 7;
        int pos = atomicAdd(&sh.p.cur[sb], 1);
        if (pos < SBCAP) buf[sb * SBCAP + pos] = s | ((d & 127) << 17);
    }
}

// ---- phase B: per-SB counting sort -> exact CSR, fused dinv + zs16 ----
__global__ void k_sort(const float* __restrict__ z, const int* __restrict__ gcur,
                       const int* __restrict__ buf, int* __restrict__ csr,
                       int* __restrict__ begA, int* __restrict__ cntA,
                       float* __restrict__ ws) {
    __shared__ int pay[SBCAP];
    __shared__ int h[SB_NODES + 1];
    __shared__ int lcur[SB_NODES];
    __shared__ float sdv[SB_NODES];
    int sb = blockIdx.x, t = threadIdx.x;
    int n = gcur[sb];
    if (n > SBCAP) n = SBCAP;
    for (int i = t; i < n; i += 256) pay[i] = buf[sb * SBCAP + i];
    if (t <= SB_NODES) h[t] = 0;
    __syncthreads();
    for (int i = t; i < n; i += 256) atomicAdd(&h[(pay[i] >> 17) + 1], 1);
    __syncthreads();
    int mydeg = 0;
    if (t < SB_NODES) { mydeg = h[t + 1]; h[t + 1] = (mydeg + 3) & ~3; }
    __syncthreads();
    for (int off = 1; off <= SB_NODES; off <<= 1) {
        int v = 0;
        if (t <= SB_NODES && t >= off) v = h[t - off];
        __syncthreads();
        if (t <= SB_NODES) h[t] += v;
        __syncthreads();
    }
    int n0 = sb * SB_NODES;
    if (t < SB_NODES) {
        lcur[t] = h[t];
        float dv = rsqrtf((float)(mydeg + 1));
        sdv[t] = dv;
        if (n0 + t < N_NODES) {
            cntA[n0 + t] = mydeg;
            begA[n0 + t] = sb * SBCAP + h[t];
            ws[OFF_DINV + n0 + t] = dv;
        }
    }
    __syncthreads();
    {
        int nl = t >> 1, half = t & 1;
        int node = n0 + nl;
        if (node < N_NODES) {
            const float4* zr = (const float4*)(z + (size_t)node * 16) + 2 * half;
            float dv = sdv[nl];
            float4 a = zr[0], b = zr[1];
            a = make_float4(a.x * dv, a.y * dv, a.z * dv, a.w * dv);
            b = make_float4(b.x * dv, b.y * dv, b.z * dv, b.w * dv);
            ((float4*)((__half*)(ws + OFF_ZS16) + (size_t)node * 16))[half] = pack_h8(a, b);
        }
    }
    for (int i = t; i < n; i += 256) {
        int p = pay[i];
        int dl = p >> 17;
        int pos = atomicAdd(&lcur[dl], 1);
        if (pos < SBCAP) csr[sb * SBCAP + pos] = p & 0x1FFFF;
    }
}

// ---- pass 1: t16 = fp16( dinv_d^2 * (sum zs[s] + zs[d]) ), c ----
//      q-scheme, 32 edges/iter; sched_barrier pins all 8 gathers in flight.
__global__ void k_gather1(const int* __restrict__ cntA, const int* __restrict__ begA,
                          const int* __restrict__ csr, float* __restrict__ ws) {
    int lane = threadIdx.x & 15;
    int g = threadIdx.x >> 4;
    int q = lane & 3;
    int sub = lane >> 2;
    int d = blockIdx.x * 16 + g;
    if (d >= N_NODES) return;
    const float* dinv = ws + OFF_DINV;
    const __half* zs = (const __half*)(ws + OFF_ZS16);
    float dd = dinv[d];
    float dv2 = dd * dd;
    int deg = cntA[d];
    int beg = begA[d];
    float4 acc = make_float4(0.f, 0.f, 0.f, 0.f);
    float csum = 0.0f;
    int j = 0;
    for (; j + 32 <= deg; j += 32) {
        int4 ia = *(const int4*)(csr + beg + j + sub * 4);
        int4 ib = *(const int4*)(csr + beg + j + 16 + sub * 4);
        uint2 g0 = ((const uint2*)(zs + (size_t)ia.x * 16))[q];
        uint2 g1 = ((const uint2*)(zs + (size_t)ia.y * 16))[q];
        uint2 g2 = ((const uint2*)(zs + (size_t)ia.z * 16))[q];
        uint2 g3 = ((const uint2*)(zs + (size_t)ia.w * 16))[q];
        uint2 g4 = ((const uint2*)(zs + (size_t)ib.x * 16))[q];
        uint2 g5 = ((const uint2*)(zs + (size_t)ib.y * 16))[q];
        uint2 g6 = ((const uint2*)(zs + (size_t)ib.z * 16))[q];
        uint2 g7 = ((const uint2*)(zs + (size_t)ib.w * 16))[q];
        float dva = 0.0f, dvb = 0.0f;
        if (q == 0) {
            dva = (dinv[ia.x] + dinv[ia.y]) + (dinv[ia.z] + dinv[ia.w]);
            dvb = (dinv[ib.x] + dinv[ib.y]) + (dinv[ib.z] + dinv[ib.w]);
        }
        __builtin_amdgcn_sched_barrier(0);   // keep all gathers in flight
        acc4(acc, g0); acc4(acc, g1); acc4(acc, g2); acc4(acc, g3);
        acc4(acc, g4); acc4(acc, g5); acc4(acc, g6); acc4(acc, g7);
        csum += dva + dvb;
    }
    for (; j + 16 <= deg; j += 16) {
        int4 idx = *(const int4*)(csr + beg + j + sub * 4);
        uint2 g0 = ((const uint2*)(zs + (size_t)idx.x * 16))[q];
        uint2 g1 = ((const uint2*)(zs + (size_t)idx.y * 16))[q];
        uint2 g2 = ((const uint2*)(zs + (size_t)idx.z * 16))[q];
        uint2 g3 = ((const uint2*)(zs + (size_t)idx.w * 16))[q];
        acc4(acc, g0); acc4(acc, g1); acc4(acc, g2); acc4(acc, g3);
        if (q == 0) csum += (dinv[idx.x] + dinv[idx.y]) + (dinv[idx.z] + dinv[idx.w]);
    }
    for (int t = j + sub; t < deg; t += 4) {
        int s0 = csr[beg + t];
        acc4(acc, ((const uint2*)(zs + (size_t)s0 * 16))[q]);
        if (q == 0) csum += dinv[s0];
    }
    #pragma unroll
    for (int off = 4; off <= 8; off <<= 1) {
        acc.x += __shfl_xor(acc.x, off, 64);
        acc.y += __shfl_xor(acc.y, off, 64);
        acc.z += __shfl_xor(acc.z, off, 64);
        acc.w += __shfl_xor(acc.w, off, 64);
        csum  += __shfl_xor(csum,  off, 64);
    }
    if (sub == 0) {
        float4 zrow = h4_to_f4(((const uint2*)(zs + (size_t)d * 16))[q]);
        float4 o = make_float4(dv2 * (acc.x + zrow.x), dv2 * (acc.y + zrow.y),
                               dv2 * (acc.z + zrow.z), dv2 * (acc.w + zrow.w));
        ((uint2*)((__half*)(ws + OFF_T16) + (size_t)d * 16))[q] = f4_to_h4(o);
        if (q == 0) (ws + OFF_C)[d] = dd * csum + dv2;
    }
}

// ---- pass 2: u = dd * (sum t16[s] + t16[d]) -> U fp32 (unfused; the fused
//      epilogue ran 16-of-64-lanes divergent and cost ~17 µs vs separate pack) ----
__global__ void k_gather2(const int* __restrict__ cntA, const int* __restrict__ begA,
                          const int* __restrict__ csr, float* __restrict__ ws) {
    int lane = threadIdx.x & 15;
    int g = threadIdx.x >> 4;
    int q = lane & 3;
    int sub = lane >> 2;
    int d = blockIdx.x * 16 + g;
    if (d >= N_NODES) return;
    const float* dinv = ws + OFF_DINV;
    const __half* t16 = (const __half*)(ws + OFF_T16);
    float dd = dinv[d];
    int deg = cntA[d];
    int beg = begA[d];
    float4 acc = make_float4(0.f, 0.f, 0.f, 0.f);
    int j = 0;
    for (; j + 32 <= deg; j += 32) {
        int4 ia = *(const int4*)(csr + beg + j + sub * 4);
        int4 ib = *(const int4*)(csr + beg + j + 16 + sub * 4);
        uint2 g0 = ((const uint2*)(t16 + (size_t)ia.x * 16))[q];
        uint2 g1 = ((const uint2*)(t16 + (size_t)ia.y * 16))[q];
        uint2 g2 = ((const uint2*)(t16 + (size_t)ia.z * 16))[q];
        uint2 g3 = ((const uint2*)(t16 + (size_t)ia.w * 16))[q];
        uint2 g4 = ((const uint2*)(t16 + (size_t)ib.x * 16))[q];
        uint2 g5 = ((const uint2*)(t16 + (size_t)ib.y * 16))[q];
        uint2 g6 = ((const uint2*)(t16 + (size_t)ib.z * 16))[q];
        uint2 g7 = ((const uint2*)(t16 + (size_t)ib.w * 16))[q];
        __builtin_amdgcn_sched_barrier(0);   // keep all gathers in flight
        acc4(acc, g0); acc4(acc, g1); acc4(acc, g2); acc4(acc, g3);
        acc4(acc, g4); acc4(acc, g5); acc4(acc, g6); acc4(acc, g7);
    }
    for (; j + 16 <= deg; j += 16) {
        int4 idx = *(const int4*)(csr + beg + j + sub * 4);
        uint2 g0 = ((const uint2*)(t16 + (size_t)idx.x * 16))[q];
        uint2 g1 = ((const uint2*)(t16 + (size_t)idx.y * 16))[q];
        uint2 g2 = ((const uint2*)(t16 + (size_t)idx.z * 16))[q];
        uint2 g3 = ((const uint2*)(t16 + (size_t)idx.w * 16))[q];
        acc4(acc, g0); acc4(acc, g1); acc4(acc, g2); acc4(acc, g3);
    }
    for (int t = j + sub; t < deg; t += 4) {
        int s0 = csr[beg + t];
        acc4(acc, ((const uint2*)(t16 + (size_t)s0 * 16))[q]);
    }
    #pragma unroll
    for (int off = 4; off <= 8; off <<= 1) {
        acc.x += __shfl_xor(acc.x, off, 64);
        acc.y += __shfl_xor(acc.y, off, 64);
        acc.z += __shfl_xor(acc.z, off, 64);
        acc.w += __shfl_xor(acc.w, off, 64);
    }
    if (sub == 0) {
        float4 trow = h4_to_f4(((const uint2*)(t16 + (size_t)d * 16))[q]);
        float4 o = make_float4(dd * (acc.x + trow.x), dd * (acc.y + trow.y),
                               dd * (acc.z + trow.z), dd * (acc.w + trow.w));
        ((float4*)(ws + OFF_U + (size_t)d * 16))[q] = o;
    }
}

// ---- per node (separate, full-width streaming): ytab + stab ----
__global__ void k_pack(float* __restrict__ ws) {
    __shared__ float sL[256];
    __shared__ float spr[16];
    __shared__ float spb[16];
    __shared__ float sprm[8];
    int tid = threadIdx.x;
    sL[tid] = ws[OFF_L + tid];
    if (tid < 16) { spr[tid] = ws[OFF_PR + tid]; spb[tid] = ws[OFF_PB + tid]; }
    if (tid < 8) sprm[tid] = ws[OFF_ABG + tid];
    __syncthreads();
    int i = blockIdx.x * blockDim.x + tid;
    if (i >= N_NODES) return;
    const float* u = ws + OFF_U;
    const float* c = ws + OFF_C;
    float ur[16];
    const float4* urow = (const float4*)(u + (size_t)i * 16);
    #pragma unroll
    for (int m = 0; m < 4; m++) {
        float4 a = urow[m];
        ur[4 * m + 0] = a.x; ur[4 * m + 1] = a.y;
        ur[4 * m + 2] = a.z; ur[4 * m + 3] = a.w;
    }
    float A = 0.0f, B = 0.0f;
    #pragma unroll
    for (int kk = 0; kk < 16; kk++) { A += ur[kk] * spr[kk]; B += ur[kk] * spb[kk]; }
    float y[16];
    #pragma unroll
    for (int j = 0; j < 16; j++) {
        float accv = 0.0f;
        #pragma unroll
        for (int kk = 0; kk < 16; kk++) accv += ur[kk] * sL[kk * 16 + j];
        y[j] = accv;
    }
    float beta = sprm[0], gh = sprm[1], lp = sprm[2], lm = sprm[3];
    float k1 = sprm[4], k2 = sprm[5];
    float ci = c[i];
    float Ap = A + beta;
    float Bp = B + gh;
    float r1 = k1 * (lp * ci + Ap);
    float r2 = k2 * (lm * ci + Ap);
    const float inv_s2 = 0.70710678118654752f;
    float r3 = (Bp + 1.0f) * inv_s2;
    float r4 = (Bp - 1.0f) * inv_s2;
    float4* yt = (float4*)(ws + OFF_YT);
    yt[2 * i]     = pack_h8(make_float4(y[0], y[1], y[2], y[3]),
                            make_float4(y[4], y[5], y[6], y[7]));
    yt[2 * i + 1] = pack_h8(make_float4(y[8], y[9], y[10], y[11]),
                            make_float4(y[12], y[13], y[14], y[15]));
    ((uint2*)(ws + OFF_ST))[i] = make_uint2(h2bits(r1, r2), h2bits(r3, r4));
}

// ---- decoder, 1 edge per thread (best measured: 65.7 µs) ----
__global__ void k_decode(const int* __restrict__ src, const int* __restrict__ dst,
                         const float* __restrict__ ws, float* __restrict__ out) {
    int e = blockIdx.x * 256 + threadIdx.x;   // GRID_DEC*256 == N_EDGES exactly
    const float4* yt = (const float4*)(ws + OFF_YT);
    const uint2*  st = (const uint2*)(ws + OFF_ST);
    int s = __builtin_nontemporal_load(src + e);
    int d = __builtin_nontemporal_load(dst + e);
    float4 sy0 = yt[2 * (size_t)s];
    float4 sy1 = yt[2 * (size_t)s + 1];
    float4 dy0 = yt[2 * (size_t)d];
    float4 dy1 = yt[2 * (size_t)d + 1];
    uint2  ssc = st[s];
    uint2  dsc = st[d];
    __builtin_amdgcn_sched_barrier(0);   // all 6 gathers stay in flight
    float v = hdot8f(sy0, dy0) + hdot8f(sy1, dy1);
    float2 ra = bits2f2(ssc.x), rb = bits2f2(dsc.x);
    float2 rc = bits2f2(ssc.y), rd = bits2f2(dsc.y);
    v += ra.x * rb.x - ra.y * rb.y + rc.x * rd.x - rc.y * rd.y;
    __builtin_nontemporal_store(1.0f / (1.0f + expf(-v)), out + e);
}

extern "C" void kernel_launch(void* const* d_in, const int* in_sizes, int n_in,
                              void* d_out, int out_size, void* d_ws, size_t ws_size,
                              hipStream_t stream) {
    const float* z  = (const float*)d_in[0];
    const int*   ei = (const int*)d_in[1];
    const float* W1 = (const float*)d_in[2];
    const float* b1 = (const float*)d_in[3];
    const float* W2 = (const float*)d_in[4];
    const float* b2 = (const float*)d_in[5];
    float* out = (float*)d_out;
    float* ws  = (float*)d_ws;
    int*   wi  = (int*)(ws + FLOAT_TOTAL);

    const int* src = ei;
    const int* dst = ei + N_EDGES;

    int* gcur = wi + IOFF_GCUR;
    int* begA = wi + IOFF_BEG;
    int* cntA = wi + IOFF_CNT;
    int* buf  = wi + IOFF_BUF;
    int* csr  = wi + IOFF_CSR;

    hipMemsetAsync(gcur, 0, 1024 * sizeof(int), stream);
    k_part    <<<PART_BLOCKS + 1, PART_THREADS, 0, stream>>>(src, dst, gcur, buf,
                                                             W1, b1, W2, b2, ws);
    k_sort    <<<NSB, 256, 0, stream>>>(z, gcur, buf, csr, begA, cntA, ws);
    k_gather1 <<<GRID_G, 256, 0, stream>>>(cntA, begA, csr, ws);
    k_gather2 <<<GRID_G, 256, 0, stream>>>(cntA, begA, csr, ws);
    k_pack    <<<GRID_N, 256, 0, stream>>>(ws);
    k_decode  <<<GRID_DEC, 256, 0, stream>>>(src, dst, ws, out);
}

// Round 12
// 281.326 us; speedup vs baseline: 1.1476x; 1.0095x over previous
//
#include <hip/hip_runtime.h>
#include <hip/hip_fp16.h>
#include <math.h>

#define N_NODES 100000
#define N_EDGES 3200000
#define GRID_N 391        // ceil(100000/256)
#define GRID_G 6250       // ceil(100000/16)
#define NSB 782           // ceil(100000/128) super-buckets
#define SB_NODES 128
#define SBCAP 5120        // mean 4096, std 64 -> +16 sigma
#define E_BLK 12800       // edges per k_part block (250*12800 == N_EDGES exactly)
#define CH_E 6400         // local-sort chunk (2 chunks/block keeps LDS at 38 KB)
#define PART_BLOCKS 250
#define PART_THREADS 1024
#define GRID_DEC 12500    // 3.2M / 256, 1 edge per thread

// ---------------- ws float layout (element offsets) ----------------
#define OFF_DINV 0
#define OFF_C    100016
#define OFF_ZS16 200032      // 100000 x 16 halfs (dinv-scaled z)
#define OFF_T16  1000048     // 100000 x 16 halfs
#define OFF_U    1800064     // 100000 x 16 fp32
#define OFF_YT   3400080     // 100000 x 32B (16 fp16), 16B-aligned
#define OFF_ST   4200080     // 100000 x 8B (4 fp16: r1,r2,r3,r4)
#define OFF_PR   6604720
#define OFF_PB   6604736
#define OFF_ABG  6604752     // beta, gamma/2, lam+, lam-, k1, k2
#define OFF_L    6604768     // 16x16 Cholesky factor of G
#define FLOAT_TOTAL 6605024
// int region (elements into (int*)(ws + FLOAT_TOTAL))
#define IOFF_GCUR 0
#define IOFF_BEG  1024
#define IOFF_CNT  101024
#define IOFF_BUF  201024     // 782*5120
#define IOFF_CSR  4204864    // 782*5120
// ws total ~59 MB

// ---- half helpers ----
__device__ inline float4 h4_to_f4(uint2 v) {
    __half2 a = *reinterpret_cast<__half2*>(&v.x);
    __half2 b = *reinterpret_cast<__half2*>(&v.y);
    float2 fa = __half22float2(a), fb = __half22float2(b);
    return make_float4(fa.x, fa.y, fb.x, fb.y);
}
__device__ inline uint2 f4_to_h4(float4 f) {
    uint2 r;
    __half2 a = __floats2half2_rn(f.x, f.y);
    __half2 b = __floats2half2_rn(f.z, f.w);
    r.x = *reinterpret_cast<unsigned*>(&a);
    r.y = *reinterpret_cast<unsigned*>(&b);
    return r;
}
__device__ inline float4 pack_h8(float4 a, float4 b) {
    float4 r;
    __half2* p = reinterpret_cast<__half2*>(&r);
    p[0] = __floats2half2_rn(a.x, a.y);
    p[1] = __floats2half2_rn(a.z, a.w);
    p[2] = __floats2half2_rn(b.x, b.y);
    p[3] = __floats2half2_rn(b.z, b.w);
    return r;
}
__device__ inline unsigned h2bits(float a, float b) {
    __half2 h = __floats2half2_rn(a, b);
    return *reinterpret_cast<unsigned*>(&h);
}
__device__ inline float2 bits2f2(unsigned v) {
    __half2 h = *reinterpret_cast<__half2*>(&v);
    return __half22float2(h);
}
__device__ inline float hdot8f(float4 a, float4 b) {
    const __half2* pa = reinterpret_cast<const __half2*>(&a);
    const __half2* pb = reinterpret_cast<const __half2*>(&b);
    float s = 0.0f;
    #pragma unroll
    for (int i = 0; i < 4; i++) {
        float2 fa = __half22float2(pa[i]);
        float2 fb = __half22float2(pb[i]);
        s += fa.x * fb.x + fa.y * fb.y;
    }
    return s;
}
__device__ inline void acc4(float4& acc, uint2 g) {
    float4 f = h4_to_f4(g);
    acc.x += f.x; acc.y += f.y; acc.z += f.z; acc.w += f.w;
}

// ---- shared-memory unions for the merged part+consts kernel ----
struct ConstsSh {
    float sW1t[16 * 256];
    float sM[16 * 257];
    float sb1[256];
    float sb2[256];
    float sR[256];
    float sG[256];
    float sLf[256];
};
// local counting-sort staging (per 6400-edge chunk): 38.1 KB total
struct PartSh {
    int h2[2][NSB];      // 6.3 KB
    int pref[NSB + 1];   // 3.1 KB  (scan -> bucket starts -> cursors -> ends)
    int gbase[NSB];      // 3.1 KB
    int pay[CH_E];       // 25.6 KB (chunk's edges, sorted by super-bucket)
};

// ---- phase A: block-local counting sort (2 chunks) -> coalesced run writes.
//      Extra block (blockIdx == PART_BLOCKS) computes weight-constants. ----
__global__ void __launch_bounds__(PART_THREADS)
k_part(const int* __restrict__ src, const int* __restrict__ dst,
       int* __restrict__ gcur, int* __restrict__ buf,
       const float* __restrict__ W1, const float* __restrict__ b1,
       const float* __restrict__ W2, const float* __restrict__ b2,
       float* __restrict__ ws) {
    __shared__ union { ConstsSh c; PartSh p; } sh;
    int t = threadIdx.x;

    if (blockIdx.x == PART_BLOCKS) {
        bool act = t < 256;
        if (act) {
            #pragma unroll
            for (int r = 0; r < 16; r++)
                sh.c.sW1t[t * 16 + r] = W1[r * 256 + t];
            sh.c.sb1[t] = b1[t];
            sh.c.sb2[t] = b2[t];
        }
        __syncthreads();
        if (act) {
            float acc[16];
            #pragma unroll
            for (int i = 0; i < 16; i++) acc[i] = 0.0f;
            float raccv = 0.0f;
            for (int kk = 0; kk < 256; kk += 8) {
                float w2v[8];
                #pragma unroll
                for (int u = 0; u < 8; u++)
                    w2v[u] = W2[(kk + u) * 256 + t];
                #pragma unroll
                for (int u = 0; u < 8; u++) {
                    #pragma unroll
                    for (int i = 0; i < 16; i++)
                        acc[i] += sh.c.sW1t[(kk + u) * 16 + i] * w2v[u];
                    raccv += sh.c.sb1[kk + u] * w2v[u];
                }
            }
            #pragma unroll
            for (int i = 0; i < 16; i++) sh.c.sM[i * 257 + t] = acc[i];
            sh.c.sR[t] = raccv;
        }
        __syncthreads();
        if (act) {
            int i = t >> 4, j = t & 15;
            float gg = 0.0f;
            for (int tt = 0; tt < 256; tt++)
                gg += sh.c.sM[i * 257 + tt] * sh.c.sM[j * 257 + tt];
            sh.c.sG[t] = gg;
        }
        if (t < 16) {
            float a = 0.0f, b = 0.0f;
            for (int tt = 0; tt < 256; tt++) {
                a += sh.c.sM[t * 257 + tt] * sh.c.sR[tt];
                b += sh.c.sM[t * 257 + tt] * sh.c.sb2[tt];
            }
            ws[OFF_PR + t] = a;
            ws[OFF_PB + t] = b;
        }
        if (t == 0) {
            float al = 0.0f, be = 0.0f, ga = 0.0f;
            for (int tt = 0; tt < 256; tt++) {
                al += sh.c.sR[tt] * sh.c.sR[tt];
                be += sh.c.sR[tt] * sh.c.sb2[tt];
                ga += sh.c.sb2[tt] * sh.c.sb2[tt];
            }
            float disc = sqrtf(al * al + 4.0f);
            float lp = 0.5f * (al + disc);
            float lm = 0.5f * (al - disc);
            float k1 = sqrtf(lp / (lp * lp + 1.0f));
            float k2 = sqrtf(-lm / (lm * lm + 1.0f));
            ws[OFF_ABG + 0] = be;
            ws[OFF_ABG + 1] = 0.5f * ga;
            ws[OFF_ABG + 2] = lp;
            ws[OFF_ABG + 3] = lm;
            ws[OFF_ABG + 4] = k1;
            ws[OFF_ABG + 5] = k2;
        }
        __syncthreads();
        if (act) sh.c.sLf[t] = 0.0f;
        __syncthreads();
        // parallel Cholesky: 16 steps, column-parallel
        for (int j = 0; j < 16; j++) {
            if (t == j) {
                float s = sh.c.sG[j * 16 + j];
                for (int k = 0; k < j; k++)
                    s -= sh.c.sLf[j * 16 + k] * sh.c.sLf[j * 16 + k];
                sh.c.sLf[j * 16 + j] = sqrtf(fmaxf(s, 1e-20f));
            }
            __syncthreads();
            if (t > j && t < 16) {
                float s = sh.c.sG[t * 16 + j];
                for (int k = 0; k < j; k++)
                    s -= sh.c.sLf[t * 16 + k] * sh.c.sLf[j * 16 + k];
                sh.c.sLf[t * 16 + j] = s / sh.c.sLf[j * 16 + j];
            }
            __syncthreads();
        }
        if (act) ws[OFF_L + t] = sh.c.sLf[t];
        return;
    }

    // ===== binning path: local counting sort, 2 chunks of 6400 edges =====
    int cp = t >> 9;   // 2 hist copies
    for (int chunk = 0; chunk < 2; chunk++) {
        int cbase = blockIdx.x * E_BLK + chunk * CH_E;
        for (int i = t; i < 2 * NSB; i += PART_THREADS) ((int*)sh.p.h2)[i] = 0;
        __syncthreads();
        // pass 1: count
        for (int i = t; i < CH_E; i += PART_THREADS) {
            int e = cbase + i;
            if (e < N_EDGES)
                atomicAdd(&sh.p.h2[cp][__builtin_nontemporal_load(dst + e) >> 7], 1);
        }
        __syncthreads();
        // prefix: pref[0]=0, pref[i+1]=cnt_i, inclusive scan -> bucket starts
        if (t == 0) sh.p.pref[0] = 0;
        if (t < NSB) sh.p.pref[t + 1] = sh.p.h2[0][t] + sh.p.h2[1][t];
        __syncthreads();
        for (int off = 1; off <= NSB; off <<= 1) {
            int v = 0;
            if (t <= NSB && t >= off) v = sh.p.pref[t - off];
            __syncthreads();
            if (t <= NSB) sh.p.pref[t] += v;
            __syncthreads();
        }
        // pass 2: scatter into LDS, sorted by sb (pref[sb] = running cursor)
        for (int i = t; i < CH_E; i += PART_THREADS) {
            int e = cbase + i;
            if (e >= N_EDGES) continue;
            int d = __builtin_nontemporal_load(dst + e);
            int s = __builtin_nontemporal_load(src + e);
            int sb = d >> 7;
            int pos = atomicAdd(&sh.p.pref[sb], 1);
            sh.p.pay[pos] = s | ((d & 127) << 17);
        }
        __syncthreads();
        // pass 3: reserve one contiguous global run per bucket.
        // After pass 2: pref[sb] == end(sb); start(sb) == (sb? pref[sb-1] : 0).
        if (t < NSB) {
            int end   = sh.p.pref[t];
            int start = (t == 0) ? 0 : sh.p.pref[t - 1];
            int cnt   = end - start;
            sh.p.gbase[t] = (cnt > 0) ? atomicAdd(&gcur[t], cnt) : 0;
        }
        __syncthreads();
        int tot = sh.p.pref[NSB];   // untouched by pass 2 (sb < NSB)
        // pass 4: coalesced copy-out; consecutive k in a bucket -> consecutive addrs
        for (int k = t; k < tot; k += PART_THREADS) {
            int lo = 0, hi = NSB - 1;          // smallest sb with end(sb) > k
            while (lo < hi) {
                int mid = (lo + hi) >> 1;
                if (sh.p.pref[mid] > k) hi = mid; else lo = mid + 1;
            }
            int sb  = lo;
            int ofs = k - ((sb == 0) ? 0 : sh.p.pref[sb - 1]);
            int p   = sh.p.gbase[sb] + ofs;
            if (p < SBCAP) buf[sb * SBCAP + p] = sh.p.pay[k];
        }
        __syncthreads();   // pay/pref/gbase reads done before next chunk reuses
    }
}

// ---- phase B: per-SB counting sort -> exact CSR, fused dinv + zs16 ----
__global__ void k_sort(const float* __restrict__ z, const int* __restrict__ gcur,
                       const int* __restrict__ buf, int* __restrict__ csr,
                       int* __restrict__ begA, int* __restrict__ cntA,
                       float* __restrict__ ws) {
    __shared__ int pay[SBCAP];
    __shared__ int h[SB_NODES + 1];
    __shared__ int lcur[SB_NODES];
    __shared__ float sdv[SB_NODES];
    int sb = blockIdx.x, t = threadIdx.x;
    int n = gcur[sb];
    if (n > SBCAP) n = SBCAP;
    for (int i = t; i < n; i += 256) pay[i] = buf[sb * SBCAP + i];
    if (t <= SB_NODES) h[t] = 0;
    __syncthreads();
    for (int i = t; i < n; i += 256) atomicAdd(&h[(pay[i] >> 17) + 1], 1);
    __syncthreads();
    int mydeg = 0;
    if (t < SB_NODES) { mydeg = h[t + 1]; h[t + 1] = (mydeg + 3) & ~3; }
    __syncthreads();
    for (int off = 1; off <= SB_NODES; off <<= 1) {
        int v = 0;
        if (t <= SB_NODES && t >= off) v = h[t - off];
        __syncthreads();
        if (t <= SB_NODES) h[t] += v;
        __syncthreads();
    }
    int n0 = sb * SB_NODES;
    if (t < SB_NODES) {
        lcur[t] = h[t];
        float dv = rsqrtf((float)(mydeg + 1));
        sdv[t] = dv;
        if (n0 + t < N_NODES) {
            cntA[n0 + t] = mydeg;
            begA[n0 + t] = sb * SBCAP + h[t];
            ws[OFF_DINV + n0 + t] = dv;
        }
    }
    __syncthreads();
    {
        int nl = t >> 1, half = t & 1;
        int node = n0 + nl;
        if (node < N_NODES) {
            const float4* zr = (const float4*)(z + (size_t)node * 16) + 2 * half;
            float dv = sdv[nl];
            float4 a = zr[0], b = zr[1];
            a = make_float4(a.x * dv, a.y * dv, a.z * dv, a.w * dv);
            b = make_float4(b.x * dv, b.y * dv, b.z * dv, b.w * dv);
            ((float4*)((__half*)(ws + OFF_ZS16) + (size_t)node * 16))[half] = pack_h8(a, b);
        }
    }
    for (int i = t; i < n; i += 256) {
        int p = pay[i];
        int dl = p >> 17;
        int pos = atomicAdd(&lcur[dl], 1);
        if (pos < SBCAP) csr[sb * SBCAP + pos] = p & 0x1FFFF;
    }
}

// ---- pass 1: t16 = fp16( dinv_d^2 * (sum zs[s] + zs[d]) ), c ----
//      q-scheme, 32 edges/iter; sched_barrier pins all 8 gathers in flight.
__global__ void k_gather1(const int* __restrict__ cntA, const int* __restrict__ begA,
                          const int* __restrict__ csr, float* __restrict__ ws) {
    int lane = threadIdx.x & 15;
    int g = threadIdx.x >> 4;
    int q = lane & 3;
    int sub = lane >> 2;
    int d = blockIdx.x * 16 + g;
    if (d >= N_NODES) return;
    const float* dinv = ws + OFF_DINV;
    const __half* zs = (const __half*)(ws + OFF_ZS16);
    float dd = dinv[d];
    float dv2 = dd * dd;
    int deg = cntA[d];
    int beg = begA[d];
    float4 acc = make_float4(0.f, 0.f, 0.f, 0.f);
    float csum = 0.0f;
    int j = 0;
    for (; j + 32 <= deg; j += 32) {
        int4 ia = *(const int4*)(csr + beg + j + sub * 4);
        int4 ib = *(const int4*)(csr + beg + j + 16 + sub * 4);
        uint2 g0 = ((const uint2*)(zs + (size_t)ia.x * 16))[q];
        uint2 g1 = ((const uint2*)(zs + (size_t)ia.y * 16))[q];
        uint2 g2 = ((const uint2*)(zs + (size_t)ia.z * 16))[q];
        uint2 g3 = ((const uint2*)(zs + (size_t)ia.w * 16))[q];
        uint2 g4 = ((const uint2*)(zs + (size_t)ib.x * 16))[q];
        uint2 g5 = ((const uint2*)(zs + (size_t)ib.y * 16))[q];
        uint2 g6 = ((const uint2*)(zs + (size_t)ib.z * 16))[q];
        uint2 g7 = ((const uint2*)(zs + (size_t)ib.w * 16))[q];
        float dva = 0.0f, dvb = 0.0f;
        if (q == 0) {
            dva = (dinv[ia.x] + dinv[ia.y]) + (dinv[ia.z] + dinv[ia.w]);
            dvb = (dinv[ib.x] + dinv[ib.y]) + (dinv[ib.z] + dinv[ib.w]);
        }
        __builtin_amdgcn_sched_barrier(0);   // keep all gathers in flight
        acc4(acc, g0); acc4(acc, g1); acc4(acc, g2); acc4(acc, g3);
        acc4(acc, g4); acc4(acc, g5); acc4(acc, g6); acc4(acc, g7);
        csum += dva + dvb;
    }
    for (; j + 16 <= deg; j += 16) {
        int4 idx = *(const int4*)(csr + beg + j + sub * 4);
        uint2 g0 = ((const uint2*)(zs + (size_t)idx.x * 16))[q];
        uint2 g1 = ((const uint2*)(zs + (size_t)idx.y * 16))[q];
        uint2 g2 = ((const uint2*)(zs + (size_t)idx.z * 16))[q];
        uint2 g3 = ((const uint2*)(zs + (size_t)idx.w * 16))[q];
        acc4(acc, g0); acc4(acc, g1); acc4(acc, g2); acc4(acc, g3);
        if (q == 0) csum += (dinv[idx.x] + dinv[idx.y]) + (dinv[idx.z] + dinv[idx.w]);
    }
    for (int t = j + sub; t < deg; t += 4) {
        int s0 = csr[beg + t];
        acc4(acc, ((const uint2*)(zs + (size_t)s0 * 16))[q]);
        if (q == 0) csum += dinv[s0];
    }
    #pragma unroll
    for (int off = 4; off <= 8; off <<= 1) {
        acc.x += __shfl_xor(acc.x, off, 64);
        acc.y += __shfl_xor(acc.y, off, 64);
        acc.z += __shfl_xor(acc.z, off, 64);
        acc.w += __shfl_xor(acc.w, off, 64);
        csum  += __shfl_xor(csum,  off, 64);
    }
    if (sub == 0) {
        float4 zrow = h4_to_f4(((const uint2*)(zs + (size_t)d * 16))[q]);
        float4 o = make_float4(dv2 * (acc.x + zrow.x), dv2 * (acc.y + zrow.y),
                               dv2 * (acc.z + zrow.z), dv2 * (acc.w + zrow.w));
        ((uint2*)((__half*)(ws + OFF_T16) + (size_t)d * 16))[q] = f4_to_h4(o);
        if (q == 0) (ws + OFF_C)[d] = dd * csum + dv2;
    }
}

// ---- pass 2: u = dd * (sum t16[s] + t16[d]) -> U fp32 (unfused) ----
__global__ void k_gather2(const int* __restrict__ cntA, const int* __restrict__ begA,
                          const int* __restrict__ csr, float* __restrict__ ws) {
    int lane = threadIdx.x & 15;
    int g = threadIdx.x >> 4;
    int q = lane & 3;
    int sub = lane >> 2;
    int d = blockIdx.x * 16 + g;
    if (d >= N_NODES) return;
    const float* dinv = ws + OFF_DINV;
    const __half* t16 = (const __half*)(ws + OFF_T16);
    float dd = dinv[d];
    int deg = cntA[d];
    int beg = begA[d];
    float4 acc = make_float4(0.f, 0.f, 0.f, 0.f);
    int j = 0;
    for (; j + 32 <= deg; j += 32) {
        int4 ia = *(const int4*)(csr + beg + j + sub * 4);
        int4 ib = *(const int4*)(csr + beg + j + 16 + sub * 4);
        uint2 g0 = ((const uint2*)(t16 + (size_t)ia.x * 16))[q];
        uint2 g1 = ((const uint2*)(t16 + (size_t)ia.y * 16))[q];
        uint2 g2 = ((const uint2*)(t16 + (size_t)ia.z * 16))[q];
        uint2 g3 = ((const uint2*)(t16 + (size_t)ia.w * 16))[q];
        uint2 g4 = ((const uint2*)(t16 + (size_t)ib.x * 16))[q];
        uint2 g5 = ((const uint2*)(t16 + (size_t)ib.y * 16))[q];
        uint2 g6 = ((const uint2*)(t16 + (size_t)ib.z * 16))[q];
        uint2 g7 = ((const uint2*)(t16 + (size_t)ib.w * 16))[q];
        __builtin_amdgcn_sched_barrier(0);   // keep all gathers in flight
        acc4(acc, g0); acc4(acc, g1); acc4(acc, g2); acc4(acc, g3);
        acc4(acc, g4); acc4(acc, g5); acc4(acc, g6); acc4(acc, g7);
    }
    for (; j + 16 <= deg; j += 16) {
        int4 idx = *(const int4*)(csr + beg + j + sub * 4);
        uint2 g0 = ((const uint2*)(t16 + (size_t)idx.x * 16))[q];
        uint2 g1 = ((const uint2*)(t16 + (size_t)idx.y * 16))[q];
        uint2 g2 = ((const uint2*)(t16 + (size_t)idx.z * 16))[q];
        uint2 g3 = ((const uint2*)(t16 + (size_t)idx.w * 16))[q];
        acc4(acc, g0); acc4(acc, g1); acc4(acc, g2); acc4(acc, g3);
    }
    for (int t = j + sub; t < deg; t += 4) {
        int s0 = csr[beg + t];
        acc4(acc, ((const uint2*)(t16 + (size_t)s0 * 16))[q]);
    }
    #pragma unroll
    for (int off = 4; off <= 8; off <<= 1) {
        acc.x += __shfl_xor(acc.x, off, 64);
        acc.y += __shfl_xor(acc.y, off, 64);
        acc.z += __shfl_xor(acc.z, off, 64);
        acc.w += __shfl_xor(acc.w, off, 64);
    }
    if (sub == 0) {
        float4 trow = h4_to_f4(((const uint2*)(t16 + (size_t)d * 16))[q]);
        float4 o = make_float4(dd * (acc.x + trow.x), dd * (acc.y + trow.y),
                               dd * (acc.z + trow.z), dd * (acc.w + trow.w));
        ((float4*)(ws + OFF_U + (size_t)d * 16))[q] = o;
    }
}

// ---- per node (separate, full-width streaming): ytab + stab ----
__global__ void k_pack(float* __restrict__ ws) {
    __shared__ float sL[256];
    __shared__ float spr[16];
    __shared__ float spb[16];
    __shared__ float sprm[8];
    int tid = threadIdx.x;
    sL[tid] = ws[OFF_L + tid];
    if (tid < 16) { spr[tid] = ws[OFF_PR + tid]; spb[tid] = ws[OFF_PB + tid]; }
    if (tid < 8) sprm[tid] = ws[OFF_ABG + tid];
    __syncthreads();
    int i = blockIdx.x * blockDim.x + tid;
    if (i >= N_NODES) return;
    const float* u = ws + OFF_U;
    const float* c = ws + OFF_C;
    float ur[16];
    const float4* urow = (const float4*)(u + (size_t)i * 16);
    #pragma unroll
    for (int m = 0; m < 4; m++) {
        float4 a = urow[m];
        ur[4 * m + 0] = a.x; ur[4 * m + 1] = a.y;
        ur[4 * m + 2] = a.z; ur[4 * m + 3] = a.w;
    }
    float A = 0.0f, B = 0.0f;
    #pragma unroll
    for (int kk = 0; kk < 16; kk++) { A += ur[kk] * spr[kk]; B += ur[kk] * spb[kk]; }
    float y[16];
    #pragma unroll
    for (int j = 0; j < 16; j++) {
        float accv = 0.0f;
        #pragma unroll
        for (int kk = 0; kk < 16; kk++) accv += ur[kk] * sL[kk * 16 + j];
        y[j] = accv;
    }
    float beta = sprm[0], gh = sprm[1], lp = sprm[2], lm = sprm[3];
    float k1 = sprm[4], k2 = sprm[5];
    float ci = c[i];
    float Ap = A + beta;
    float Bp = B + gh;
    float r1 = k1 * (lp * ci + Ap);
    float r2 = k2 * (lm * ci + Ap);
    const float inv_s2 = 0.70710678118654752f;
    float r3 = (Bp + 1.0f) * inv_s2;
    float r4 = (Bp - 1.0f) * inv_s2;
    float4* yt = (float4*)(ws + OFF_YT);
    yt[2 * i]     = pack_h8(make_float4(y[0], y[1], y[2], y[3]),
                            make_float4(y[4], y[5], y[6], y[7]));
    yt[2 * i + 1] = pack_h8(make_float4(y[8], y[9], y[10], y[11]),
                            make_float4(y[12], y[13], y[14], y[15]));
    ((uint2*)(ws + OFF_ST))[i] = make_uint2(h2bits(r1, r2), h2bits(r3, r4));
}

// ---- decoder, 1 edge per thread (best measured: 65.7 µs) ----
__global__ void k_decode(const int* __restrict__ src, const int* __restrict__ dst,
                         const float* __restrict__ ws, float* __restrict__ out) {
    int e = blockIdx.x * 256 + threadIdx.x;   // GRID_DEC*256 == N_EDGES exactly
    const float4* yt = (const float4*)(ws + OFF_YT);
    const uint2*  st = (const uint2*)(ws + OFF_ST);
    int s = __builtin_nontemporal_load(src + e);
    int d = __builtin_nontemporal_load(dst + e);
    float4 sy0 = yt[2 * (size_t)s];
    float4 sy1 = yt[2 * (size_t)s + 1];
    float4 dy0 = yt[2 * (size_t)d];
    float4 dy1 = yt[2 * (size_t)d + 1];
    uint2  ssc = st[s];
    uint2  dsc = st[d];
    __builtin_amdgcn_sched_barrier(0);   // all 6 gathers stay in flight
    float v = hdot8f(sy0, dy0) + hdot8f(sy1, dy1);
    float2 ra = bits2f2(ssc.x), rb = bits2f2(dsc.x);
    float2 rc = bits2f2(ssc.y), rd = bits2f2(dsc.y);
    v += ra.x * rb.x - ra.y * rb.y + rc.x * rd.x - rc.y * rd.y;
    __builtin_nontemporal_store(1.0f / (1.0f + expf(-v)), out + e);
}

extern "C" void kernel_launch(void* const* d_in, const int* in_sizes, int n_in,
                              void* d_out, int out_size, void* d_ws, size_t ws_size,
                              hipStream_t stream) {
    const float* z  = (const float*)d_in[0];
    const int*   ei = (const int*)d_in[1];
    const float* W1 = (const float*)d_in[2];
    const float* b1 = (const float*)d_in[3];
    const float* W2 = (const float*)d_in[4];
    const float* b2 = (const float*)d_in[5];
    float* out = (float*)d_out;
    float* ws  = (float*)d_ws;
    int*   wi  = (int*)(ws + FLOAT_TOTAL);

    const int* src = ei;
    const int* dst = ei + N_EDGES;

    int* gcur = wi + IOFF_GCUR;
    int* begA = wi + IOFF_BEG;
    int* cntA = wi + IOFF_CNT;
    int* buf  = wi + IOFF_BUF;
    int* csr  = wi + IOFF_CSR;

    hipMemsetAsync(gcur, 0, 1024 * sizeof(int), stream);
    k_part    <<<PART_BLOCKS + 1, PART_THREADS, 0, stream>>>(src, dst, gcur, buf,
                                                             W1, b1, W2, b2, ws);
    k_sort    <<<NSB, 256, 0, stream>>>(z, gcur, buf, csr, begA, cntA, ws);
    k_gather1 <<<GRID_G, 256, 0, stream>>>(cntA, begA, csr, ws);
    k_gather2 <<<GRID_G, 256, 0, stream>>>(cntA, begA, csr, ws);
    k_pack    <<<GRID_N, 256, 0, stream>>>(ws);
    k_decode  <<<GRID_DEC, 256, 0, stream>>>(src, dst, ws, out);
}

// Round 13
// 275.004 us; speedup vs baseline: 1.1739x; 1.0230x over previous
//
#include <hip/hip_runtime.h>
#include <hip/hip_fp16.h>
#include <math.h>

#define N_NODES 100000
#define N_EDGES 3200000
#define GRID_N 391        // ceil(100000/256)
#define GRID_G 6250       // ceil(100000/16)
#define NSB 782           // ceil(100000/128) super-buckets
#define SB_NODES 128
#define SBCAP 5120        // mean 4096, std 64 -> +16 sigma
#define E_BLK 12800       // edges per k_part block (250*12800 == N_EDGES exactly)
#define CH_E 6400         // local-sort chunk (2 chunks/block keeps LDS at 38 KB)
#define PART_BLOCKS 250
#define PART_THREADS 1024
#define GRID_DEC 12500    // 3.2M / 256, 1 edge per thread

// ---------------- ws float layout (element offsets) ----------------
#define OFF_DINV 0
#define OFF_C    100016
#define OFF_ZS16 200032      // 100000 x 16 halfs (dinv-scaled z)
#define OFF_T16  1000048     // 100000 x 16 halfs
#define OFF_U    1800064     // 100000 x 16 fp32
#define OFF_YT   3400080     // 100000 x 32B (16 fp16), 16B-aligned
#define OFF_ST   4200080     // 100000 x 8B (4 fp16: r1,r2,r3,r4)
#define OFF_PR   6604720
#define OFF_PB   6604736
#define OFF_ABG  6604752     // beta, gamma/2, lam+, lam-, k1, k2
#define OFF_L    6604768     // 16x16 Cholesky factor of G
#define FLOAT_TOTAL 6605024
// int region (elements into (int*)(ws + FLOAT_TOTAL))
#define IOFF_GCUR 0
#define IOFF_BEG  1024
#define IOFF_CNT  101024
#define IOFF_BUF  201024     // 782*5120
#define IOFF_CSR  4204864    // 782*5120
// ws total ~59 MB

// ---- half helpers ----
__device__ inline float4 h4_to_f4(uint2 v) {
    __half2 a = *reinterpret_cast<__half2*>(&v.x);
    __half2 b = *reinterpret_cast<__half2*>(&v.y);
    float2 fa = __half22float2(a), fb = __half22float2(b);
    return make_float4(fa.x, fa.y, fb.x, fb.y);
}
__device__ inline uint2 f4_to_h4(float4 f) {
    uint2 r;
    __half2 a = __floats2half2_rn(f.x, f.y);
    __half2 b = __floats2half2_rn(f.z, f.w);
    r.x = *reinterpret_cast<unsigned*>(&a);
    r.y = *reinterpret_cast<unsigned*>(&b);
    return r;
}
__device__ inline float4 pack_h8(float4 a, float4 b) {
    float4 r;
    __half2* p = reinterpret_cast<__half2*>(&r);
    p[0] = __floats2half2_rn(a.x, a.y);
    p[1] = __floats2half2_rn(a.z, a.w);
    p[2] = __floats2half2_rn(b.x, b.y);
    p[3] = __floats2half2_rn(b.z, b.w);
    return r;
}
__device__ inline uint4 f8_to_h8(float4 a, float4 b) {
    uint4 r;
    __half2 h0 = __floats2half2_rn(a.x, a.y);
    __half2 h1 = __floats2half2_rn(a.z, a.w);
    __half2 h2 = __floats2half2_rn(b.x, b.y);
    __half2 h3 = __floats2half2_rn(b.z, b.w);
    r.x = *reinterpret_cast<unsigned*>(&h0);
    r.y = *reinterpret_cast<unsigned*>(&h1);
    r.z = *reinterpret_cast<unsigned*>(&h2);
    r.w = *reinterpret_cast<unsigned*>(&h3);
    return r;
}
__device__ inline unsigned h2bits(float a, float b) {
    __half2 h = __floats2half2_rn(a, b);
    return *reinterpret_cast<unsigned*>(&h);
}
__device__ inline float2 bits2f2(unsigned v) {
    __half2 h = *reinterpret_cast<__half2*>(&v);
    return __half22float2(h);
}
__device__ inline float hdot8f(float4 a, float4 b) {
    const __half2* pa = reinterpret_cast<const __half2*>(&a);
    const __half2* pb = reinterpret_cast<const __half2*>(&b);
    float s = 0.0f;
    #pragma unroll
    for (int i = 0; i < 4; i++) {
        float2 fa = __half22float2(pa[i]);
        float2 fb = __half22float2(pb[i]);
        s += fa.x * fb.x + fa.y * fb.y;
    }
    return s;
}
// accumulate 8 halfs (uint4) into two float4 accumulators
__device__ inline void acc8(float4& lo, float4& hi, uint4 v) {
    float2 p0 = __half22float2(*reinterpret_cast<__half2*>(&v.x));
    float2 p1 = __half22float2(*reinterpret_cast<__half2*>(&v.y));
    float2 p2 = __half22float2(*reinterpret_cast<__half2*>(&v.z));
    float2 p3 = __half22float2(*reinterpret_cast<__half2*>(&v.w));
    lo.x += p0.x; lo.y += p0.y; lo.z += p1.x; lo.w += p1.y;
    hi.x += p2.x; hi.y += p2.y; hi.z += p3.x; hi.w += p3.y;
}

// ---- shared-memory unions for the merged part+consts kernel ----
struct ConstsSh {
    float sW1t[16 * 256];
    float sM[16 * 257];
    float sb1[256];
    float sb2[256];
    float sR[256];
    float sG[256];
    float sLf[256];
};
// local counting-sort staging (per 6400-edge chunk): 38.1 KB total
struct PartSh {
    int h2[2][NSB];      // 6.3 KB
    int pref[NSB + 1];   // 3.1 KB  (scan -> bucket starts -> cursors -> ends)
    int gbase[NSB];      // 3.1 KB
    int pay[CH_E];       // 25.6 KB (chunk's edges, sorted by super-bucket)
};

// ---- phase A: block-local counting sort (2 chunks) -> coalesced run writes.
//      Extra block (blockIdx == PART_BLOCKS) computes weight-constants. ----
__global__ void __launch_bounds__(PART_THREADS)
k_part(const int* __restrict__ src, const int* __restrict__ dst,
       int* __restrict__ gcur, int* __restrict__ buf,
       const float* __restrict__ W1, const float* __restrict__ b1,
       const float* __restrict__ W2, const float* __restrict__ b2,
       float* __restrict__ ws) {
    __shared__ union { ConstsSh c; PartSh p; } sh;
    int t = threadIdx.x;

    if (blockIdx.x == PART_BLOCKS) {
        bool act = t < 256;
        if (act) {
            #pragma unroll
            for (int r = 0; r < 16; r++)
                sh.c.sW1t[t * 16 + r] = W1[r * 256 + t];
            sh.c.sb1[t] = b1[t];
            sh.c.sb2[t] = b2[t];
        }
        __syncthreads();
        if (act) {
            float acc[16];
            #pragma unroll
            for (int i = 0; i < 16; i++) acc[i] = 0.0f;
            float raccv = 0.0f;
            for (int kk = 0; kk < 256; kk += 8) {
                float w2v[8];
                #pragma unroll
                for (int u = 0; u < 8; u++)
                    w2v[u] = W2[(kk + u) * 256 + t];
                #pragma unroll
                for (int u = 0; u < 8; u++) {
                    #pragma unroll
                    for (int i = 0; i < 16; i++)
                        acc[i] += sh.c.sW1t[(kk + u) * 16 + i] * w2v[u];
                    raccv += sh.c.sb1[kk + u] * w2v[u];
                }
            }
            #pragma unroll
            for (int i = 0; i < 16; i++) sh.c.sM[i * 257 + t] = acc[i];
            sh.c.sR[t] = raccv;
        }
        __syncthreads();
        if (act) {
            int i = t >> 4, j = t & 15;
            float gg = 0.0f;
            for (int tt = 0; tt < 256; tt++)
                gg += sh.c.sM[i * 257 + tt] * sh.c.sM[j * 257 + tt];
            sh.c.sG[t] = gg;
        }
        if (t < 16) {
            float a = 0.0f, b = 0.0f;
            for (int tt = 0; tt < 256; tt++) {
                a += sh.c.sM[t * 257 + tt] * sh.c.sR[tt];
                b += sh.c.sM[t * 257 + tt] * sh.c.sb2[tt];
            }
            ws[OFF_PR + t] = a;
            ws[OFF_PB + t] = b;
        }
        if (t == 0) {
            float al = 0.0f, be = 0.0f, ga = 0.0f;
            for (int tt = 0; tt < 256; tt++) {
                al += sh.c.sR[tt] * sh.c.sR[tt];
                be += sh.c.sR[tt] * sh.c.sb2[tt];
                ga += sh.c.sb2[tt] * sh.c.sb2[tt];
            }
            float disc = sqrtf(al * al + 4.0f);
            float lp = 0.5f * (al + disc);
            float lm = 0.5f * (al - disc);
            float k1 = sqrtf(lp / (lp * lp + 1.0f));
            float k2 = sqrtf(-lm / (lm * lm + 1.0f));
            ws[OFF_ABG + 0] = be;
            ws[OFF_ABG + 1] = 0.5f * ga;
            ws[OFF_ABG + 2] = lp;
            ws[OFF_ABG + 3] = lm;
            ws[OFF_ABG + 4] = k1;
            ws[OFF_ABG + 5] = k2;
        }
        __syncthreads();
        if (act) sh.c.sLf[t] = 0.0f;
        __syncthreads();
        // parallel Cholesky: 16 steps, column-parallel
        for (int j = 0; j < 16; j++) {
            if (t == j) {
                float s = sh.c.sG[j * 16 + j];
                for (int k = 0; k < j; k++)
                    s -= sh.c.sLf[j * 16 + k] * sh.c.sLf[j * 16 + k];
                sh.c.sLf[j * 16 + j] = sqrtf(fmaxf(s, 1e-20f));
            }
            __syncthreads();
            if (t > j && t < 16) {
                float s = sh.c.sG[t * 16 + j];
                for (int k = 0; k < j; k++)
                    s -= sh.c.sLf[t * 16 + k] * sh.c.sLf[j * 16 + k];
                sh.c.sLf[t * 16 + j] = s / sh.c.sLf[j * 16 + j];
            }
            __syncthreads();
        }
        if (act) ws[OFF_L + t] = sh.c.sLf[t];
        return;
    }

    // ===== binning path: local counting sort, 2 chunks of 6400 edges =====
    int cp = t >> 9;   // 2 hist copies
    for (int chunk = 0; chunk < 2; chunk++) {
        int cbase = blockIdx.x * E_BLK + chunk * CH_E;
        for (int i = t; i < 2 * NSB; i += PART_THREADS) ((int*)sh.p.h2)[i] = 0;
        __syncthreads();
        // pass 1: count
        for (int i = t; i < CH_E; i += PART_THREADS) {
            int e = cbase + i;
            if (e < N_EDGES)
                atomicAdd(&sh.p.h2[cp][__builtin_nontemporal_load(dst + e) >> 7], 1);
        }
        __syncthreads();
        // prefix: pref[0]=0, pref[i+1]=cnt_i, inclusive scan -> bucket starts
        if (t == 0) sh.p.pref[0] = 0;
        if (t < NSB) sh.p.pref[t + 1] = sh.p.h2[0][t] + sh.p.h2[1][t];
        __syncthreads();
        for (int off = 1; off <= NSB; off <<= 1) {
            int v = 0;
            if (t <= NSB && t >= off) v = sh.p.pref[t - off];
            __syncthreads();
            if (t <= NSB) sh.p.pref[t] += v;
            __syncthreads();
        }
        // pass 2: scatter into LDS, sorted by sb (pref[sb] = running cursor)
        for (int i = t; i < CH_E; i += PART_THREADS) {
            int e = cbase + i;
            if (e >= N_EDGES) continue;
            int d = __builtin_nontemporal_load(dst + e);
            int s = __builtin_nontemporal_load(src + e);
            int sb = d >> 7;
            int pos = atomicAdd(&sh.p.pref[sb], 1);
            sh.p.pay[pos] = s | ((d & 127) << 17);
        }
        __syncthreads();
        // pass 3: reserve one contiguous global run per bucket.
        // After pass 2: pref[sb] == end(sb); start(sb) == (sb? pref[sb-1] : 0).
        if (t < NSB) {
            int end   = sh.p.pref[t];
            int start = (t == 0) ? 0 : sh.p.pref[t - 1];
            int cnt   = end - start;
            sh.p.gbase[t] = (cnt > 0) ? atomicAdd(&gcur[t], cnt) : 0;
        }
        __syncthreads();
        int tot = sh.p.pref[NSB];   // untouched by pass 2 (sb < NSB)
        // pass 4: coalesced copy-out; consecutive k in a bucket -> consecutive addrs
        for (int k = t; k < tot; k += PART_THREADS) {
            int lo = 0, hi = NSB - 1;          // smallest sb with end(sb) > k
            while (lo < hi) {
                int mid = (lo + hi) >> 1;
                if (sh.p.pref[mid] > k) hi = mid; else lo = mid + 1;
            }
            int sb  = lo;
            int ofs = k - ((sb == 0) ? 0 : sh.p.pref[sb - 1]);
            int p   = sh.p.gbase[sb] + ofs;
            if (p < SBCAP) buf[sb * SBCAP + p] = sh.p.pay[k];
        }
        __syncthreads();   // pay/pref/gbase reads done before next chunk reuses
    }
}

// ---- phase B: per-SB counting sort -> exact CSR, fused dinv + zs16 ----
__global__ void k_sort(const float* __restrict__ z, const int* __restrict__ gcur,
                       const int* __restrict__ buf, int* __restrict__ csr,
                       int* __restrict__ begA, int* __restrict__ cntA,
                       float* __restrict__ ws) {
    __shared__ int pay[SBCAP];
    __shared__ int h[SB_NODES + 1];
    __shared__ int lcur[SB_NODES];
    __shared__ float sdv[SB_NODES];
    int sb = blockIdx.x, t = threadIdx.x;
    int n = gcur[sb];
    if (n > SBCAP) n = SBCAP;
    for (int i = t; i < n; i += 256) pay[i] = buf[sb * SBCAP + i];
    if (t <= SB_NODES) h[t] = 0;
    __syncthreads();
    for (int i = t; i < n; i += 256) atomicAdd(&h[(pay[i] >> 17) + 1], 1);
    __syncthreads();
    int mydeg = 0;
    if (t < SB_NODES) { mydeg = h[t + 1]; h[t + 1] = (mydeg + 3) & ~3; }
    __syncthreads();
    for (int off = 1; off <= SB_NODES; off <<= 1) {
        int v = 0;
        if (t <= SB_NODES && t >= off) v = h[t - off];
        __syncthreads();
        if (t <= SB_NODES) h[t] += v;
        __syncthreads();
    }
    int n0 = sb * SB_NODES;
    if (t < SB_NODES) {
        lcur[t] = h[t];
        float dv = rsqrtf((float)(mydeg + 1));
        sdv[t] = dv;
        if (n0 + t < N_NODES) {
            cntA[n0 + t] = mydeg;
            begA[n0 + t] = sb * SBCAP + h[t];
            ws[OFF_DINV + n0 + t] = dv;
        }
    }
    __syncthreads();
    {
        int nl = t >> 1, half = t & 1;
        int node = n0 + nl;
        if (node < N_NODES) {
            const float4* zr = (const float4*)(z + (size_t)node * 16) + 2 * half;
            float dv = sdv[nl];
            float4 a = zr[0], b = zr[1];
            a = make_float4(a.x * dv, a.y * dv, a.z * dv, a.w * dv);
            b = make_float4(b.x * dv, b.y * dv, b.z * dv, b.w * dv);
            ((float4*)((__half*)(ws + OFF_ZS16) + (size_t)node * 16))[half] = pack_h8(a, b);
        }
    }
    for (int i = t; i < n; i += 256) {
        int p = pay[i];
        int dl = p >> 17;
        int pos = atomicAdd(&lcur[dl], 1);
        if (pos < SBCAP) csr[sb * SBCAP + pos] = p & 0x1FFFF;
    }
}

// ---- pass 1 (half-row scheme): lanes pair up — h = lane&1 owns 16B of the
//      32B row, el = lane>>1 owns edge slots. Each gather instruction covers
//      32 distinct rows (2x the q-scheme) at ~40 VGPR (no spill; R9's 4-row
//      variant spilled at 60+ live regs). ----
__global__ void k_gather1(const int* __restrict__ cntA, const int* __restrict__ begA,
                          const int* __restrict__ csr, float* __restrict__ ws) {
    int tid = threadIdx.x;
    int lane16 = tid & 15;
    int g = tid >> 4;
    int h = lane16 & 1;      // half of row (0: dims 0-7, 1: dims 8-15)
    int el = lane16 >> 1;    // edge slot 0..7
    int d = blockIdx.x * 16 + g;
    if (d >= N_NODES) return;
    const float* dinv = ws + OFF_DINV;
    const __half* zs = (const __half*)(ws + OFF_ZS16);
    float dd = dinv[d];
    float dv2 = dd * dd;
    int deg = cntA[d];
    int beg = begA[d];
    float4 a0 = make_float4(0.f, 0.f, 0.f, 0.f), a1 = a0;
    float csum = 0.0f;
    int j = el;
    for (; j + 8 < deg; j += 16) {
        int s0 = csr[beg + j];
        int s1 = csr[beg + j + 8];
        uint4 p0 = *(const uint4*)(zs + (size_t)s0 * 16 + h * 8);
        uint4 p1 = *(const uint4*)(zs + (size_t)s1 * 16 + h * 8);
        float dv = 0.0f;
        if (h == 0) dv = dinv[s0] + dinv[s1];
        __builtin_amdgcn_sched_barrier(0);   // keep both gathers in flight
        acc8(a0, a1, p0);
        acc8(a0, a1, p1);
        csum += dv;
    }
    if (j < deg) {
        int s0 = csr[beg + j];
        uint4 p0 = *(const uint4*)(zs + (size_t)s0 * 16 + h * 8);
        float dv = (h == 0) ? dinv[s0] : 0.0f;
        __builtin_amdgcn_sched_barrier(0);
        acc8(a0, a1, p0);
        csum += dv;
    }
    // reduce over the 8 edge slots (xor 2,4,8; h preserved)
    #pragma unroll
    for (int m = 2; m <= 8; m <<= 1) {
        a0.x += __shfl_xor(a0.x, m, 64); a0.y += __shfl_xor(a0.y, m, 64);
        a0.z += __shfl_xor(a0.z, m, 64); a0.w += __shfl_xor(a0.w, m, 64);
        a1.x += __shfl_xor(a1.x, m, 64); a1.y += __shfl_xor(a1.y, m, 64);
        a1.z += __shfl_xor(a1.z, m, 64); a1.w += __shfl_xor(a1.w, m, 64);
        csum += __shfl_xor(csum, m, 64);
    }
    if (el == 0) {
        // add own row half, scale, write this lane's 16B chunk
        uint4 zq = *(const uint4*)(zs + (size_t)d * 16 + h * 8);
        float4 z0 = make_float4(0.f, 0.f, 0.f, 0.f), z1 = z0;
        acc8(z0, z1, zq);
        float4 o0 = make_float4(dv2 * (a0.x + z0.x), dv2 * (a0.y + z0.y),
                                dv2 * (a0.z + z0.z), dv2 * (a0.w + z0.w));
        float4 o1 = make_float4(dv2 * (a1.x + z1.x), dv2 * (a1.y + z1.y),
                                dv2 * (a1.z + z1.z), dv2 * (a1.w + z1.w));
        ((uint4*)((__half*)(ws + OFF_T16) + (size_t)d * 16))[h] = f8_to_h8(o0, o1);
        if (h == 0) (ws + OFF_C)[d] = dd * csum + dv2;
    }
}

// ---- pass 2 (half-row scheme): u = dd * (sum t16[s] + t16[d]) -> U fp32 ----
__global__ void k_gather2(const int* __restrict__ cntA, const int* __restrict__ begA,
                          const int* __restrict__ csr, float* __restrict__ ws) {
    int tid = threadIdx.x;
    int lane16 = tid & 15;
    int g = tid >> 4;
    int h = lane16 & 1;
    int el = lane16 >> 1;
    int d = blockIdx.x * 16 + g;
    if (d >= N_NODES) return;
    const float* dinv = ws + OFF_DINV;
    const __half* t16 = (const __half*)(ws + OFF_T16);
    float dd = dinv[d];
    int deg = cntA[d];
    int beg = begA[d];
    float4 a0 = make_float4(0.f, 0.f, 0.f, 0.f), a1 = a0;
    int j = el;
    for (; j + 8 < deg; j += 16) {
        int s0 = csr[beg + j];
        int s1 = csr[beg + j + 8];
        uint4 p0 = *(const uint4*)(t16 + (size_t)s0 * 16 + h * 8);
        uint4 p1 = *(const uint4*)(t16 + (size_t)s1 * 16 + h * 8);
        __builtin_amdgcn_sched_barrier(0);   // keep both gathers in flight
        acc8(a0, a1, p0);
        acc8(a0, a1, p1);
    }
    if (j < deg) {
        int s0 = csr[beg + j];
        uint4 p0 = *(const uint4*)(t16 + (size_t)s0 * 16 + h * 8);
        __builtin_amdgcn_sched_barrier(0);
        acc8(a0, a1, p0);
    }
    #pragma unroll
    for (int m = 2; m <= 8; m <<= 1) {
        a0.x += __shfl_xor(a0.x, m, 64); a0.y += __shfl_xor(a0.y, m, 64);
        a0.z += __shfl_xor(a0.z, m, 64); a0.w += __shfl_xor(a0.w, m, 64);
        a1.x += __shfl_xor(a1.x, m, 64); a1.y += __shfl_xor(a1.y, m, 64);
        a1.z += __shfl_xor(a1.z, m, 64); a1.w += __shfl_xor(a1.w, m, 64);
    }
    if (el == 0) {
        uint4 tq = *(const uint4*)(t16 + (size_t)d * 16 + h * 8);
        float4 z0 = make_float4(0.f, 0.f, 0.f, 0.f), z1 = z0;
        acc8(z0, z1, tq);
        float4 o0 = make_float4(dd * (a0.x + z0.x), dd * (a0.y + z0.y),
                                dd * (a0.z + z0.z), dd * (a0.w + z0.w));
        float4 o1 = make_float4(dd * (a1.x + z1.x), dd * (a1.y + z1.y),
                                dd * (a1.z + z1.z), dd * (a1.w + z1.w));
        float4* urow = (float4*)(ws + OFF_U + (size_t)d * 16);
        urow[h * 2]     = o0;
        urow[h * 2 + 1] = o1;
    }
}

// ---- per node (separate, full-width streaming): ytab + stab ----
__global__ void k_pack(float* __restrict__ ws) {
    __shared__ float sL[256];
    __shared__ float spr[16];
    __shared__ float spb[16];
    __shared__ float sprm[8];
    int tid = threadIdx.x;
    sL[tid] = ws[OFF_L + tid];
    if (tid < 16) { spr[tid] = ws[OFF_PR + tid]; spb[tid] = ws[OFF_PB + tid]; }
    if (tid < 8) sprm[tid] = ws[OFF_ABG + tid];
    __syncthreads();
    int i = blockIdx.x * blockDim.x + tid;
    if (i >= N_NODES) return;
    const float* u = ws + OFF_U;
    const float* c = ws + OFF_C;
    float ur[16];
    const float4* urow = (const float4*)(u + (size_t)i * 16);
    #pragma unroll
    for (int m = 0; m < 4; m++) {
        float4 a = urow[m];
        ur[4 * m + 0] = a.x; ur[4 * m + 1] = a.y;
        ur[4 * m + 2] = a.z; ur[4 * m + 3] = a.w;
    }
    float A = 0.0f, B = 0.0f;
    #pragma unroll
    for (int kk = 0; kk < 16; kk++) { A += ur[kk] * spr[kk]; B += ur[kk] * spb[kk]; }
    float y[16];
    #pragma unroll
    for (int j = 0; j < 16; j++) {
        float accv = 0.0f;
        #pragma unroll
        for (int kk = 0; kk < 16; kk++) accv += ur[kk] * sL[kk * 16 + j];
        y[j] = accv;
    }
    float beta = sprm[0], gh = sprm[1], lp = sprm[2], lm = sprm[3];
    float k1 = sprm[4], k2 = sprm[5];
    float ci = c[i];
    float Ap = A + beta;
    float Bp = B + gh;
    float r1 = k1 * (lp * ci + Ap);
    float r2 = k2 * (lm * ci + Ap);
    const float inv_s2 = 0.70710678118654752f;
    float r3 = (Bp + 1.0f) * inv_s2;
    float r4 = (Bp - 1.0f) * inv_s2;
    float4* yt = (float4*)(ws + OFF_YT);
    yt[2 * i]     = pack_h8(make_float4(y[0], y[1], y[2], y[3]),
                            make_float4(y[4], y[5], y[6], y[7]));
    yt[2 * i + 1] = pack_h8(make_float4(y[8], y[9], y[10], y[11]),
                            make_float4(y[12], y[13], y[14], y[15]));
    ((uint2*)(ws + OFF_ST))[i] = make_uint2(h2bits(r1, r2), h2bits(r3, r4));
}

// ---- decoder, 1 edge per thread (best measured: 65.7 µs) ----
__global__ void k_decode(const int* __restrict__ src, const int* __restrict__ dst,
                         const float* __restrict__ ws, float* __restrict__ out) {
    int e = blockIdx.x * 256 + threadIdx.x;   // GRID_DEC*256 == N_EDGES exactly
    const float4* yt = (const float4*)(ws + OFF_YT);
    const uint2*  st = (const uint2*)(ws + OFF_ST);
    int s = __builtin_nontemporal_load(src + e);
    int d = __builtin_nontemporal_load(dst + e);
    float4 sy0 = yt[2 * (size_t)s];
    float4 sy1 = yt[2 * (size_t)s + 1];
    float4 dy0 = yt[2 * (size_t)d];
    float4 dy1 = yt[2 * (size_t)d + 1];
    uint2  ssc = st[s];
    uint2  dsc = st[d];
    __builtin_amdgcn_sched_barrier(0);   // all 6 gathers stay in flight
    float v = hdot8f(sy0, dy0) + hdot8f(sy1, dy1);
    float2 ra = bits2f2(ssc.x), rb = bits2f2(dsc.x);
    float2 rc = bits2f2(ssc.y), rd = bits2f2(dsc.y);
    v += ra.x * rb.x - ra.y * rb.y + rc.x * rd.x - rc.y * rd.y;
    __builtin_nontemporal_store(1.0f / (1.0f + expf(-v)), out + e);
}

extern "C" void kernel_launch(void* const* d_in, const int* in_sizes, int n_in,
                              void* d_out, int out_size, void* d_ws, size_t ws_size,
                              hipStream_t stream) {
    const float* z  = (const float*)d_in[0];
    const int*   ei = (const int*)d_in[1];
    const float* W1 = (const float*)d_in[2];
    const float* b1 = (const float*)d_in[3];
    const float* W2 = (const float*)d_in[4];
    const float* b2 = (const float*)d_in[5];
    float* out = (float*)d_out;
    float* ws  = (float*)d_ws;
    int*   wi  = (int*)(ws + FLOAT_TOTAL);

    const int* src = ei;
    const int* dst = ei + N_EDGES;

    int* gcur = wi + IOFF_GCUR;
    int* begA = wi + IOFF_BEG;
    int* cntA = wi + IOFF_CNT;
    int* buf  = wi + IOFF_BUF;
    int* csr  = wi + IOFF_CSR;

    hipMemsetAsync(gcur, 0, 1024 * sizeof(int), stream);
    k_part    <<<PART_BLOCKS + 1, PART_THREADS, 0, stream>>>(src, dst, gcur, buf,
                                                             W1, b1, W2, b2, ws);
    k_sort    <<<NSB, 256, 0, stream>>>(z, gcur, buf, csr, begA, cntA, ws);
    k_gather1 <<<GRID_G, 256, 0, stream>>>(cntA, begA, csr, ws);
    k_gather2 <<<GRID_G, 256, 0, stream>>>(cntA, begA, csr, ws);
    k_pack    <<<GRID_N, 256, 0, stream>>>(ws);
    k_decode  <<<GRID_DEC, 256, 0, stream>>>(src, dst, ws, out);
}